// Round 10
// baseline (1559.983 us; speedup 1.0000x reference)
//
#include <hip/hip_runtime.h>
#include <hip/hip_bf16.h>
#include <stdint.h>

#define LL 128
#define BB 64
#define VV 10000
#define EE 512
#define HH 512
#define G3 1536
#define MROWS 8192      // L*B
#define DM 8064         // (L-2)*B
#define D2H 1024
#define NPAD 10112      // 79*128
#define CC 16           // hidden cols per block per direction
#define NB 32           // gru blocks

typedef __bf16 bf16x8 __attribute__((ext_vector_type(8)));
typedef float f32x4 __attribute__((ext_vector_type(4)));
typedef unsigned int u32x4 __attribute__((ext_vector_type(4)));
typedef unsigned short u16;

static __device__ __forceinline__ float bf2f(u16 u) {
  unsigned int x = ((unsigned int)u) << 16;
  return __builtin_bit_cast(float, x);
}
static __device__ __forceinline__ u16 f2bf(float f) {
  unsigned int x = __builtin_bit_cast(unsigned int, f);
  unsigned int r = x + 0x7FFFu + ((x >> 16) & 1u);
  return (u16)(r >> 16);
}

// device-coherent (L1+L2-bypassing, visible at L3) ops — producers/flags only
static __device__ __forceinline__ void cstore16(void* p, u32x4 v) {
  asm volatile("global_store_dwordx4 %0, %1, off sc0 sc1" :: "v"(p), "v"(v) : "memory");
}
static __device__ __forceinline__ void flagstore4(void* p, int v) {
  asm volatile("global_store_dword %0, %1, off sc0 sc1" :: "v"(p), "v"(v) : "memory");
}
static __device__ __forceinline__ int flagload4(const void* p) {
  int v;
  asm volatile("global_load_dword %0, %1, off sc0 sc1\n\ts_waitcnt vmcnt(0)"
               : "=v"(v) : "v"(p) : "memory");
  return v;
}

// ---------------- cast kernels ----------------
__global__ void k_cast(const float4* __restrict__ src, ushort4* __restrict__ dst, int n4) {
  int i = blockIdx.x * blockDim.x + threadIdx.x;
  if (i < n4) {
    float4 v = src[i];
    ushort4 o;
    o.x = f2bf(v.x); o.y = f2bf(v.y); o.z = f2bf(v.z); o.w = f2bf(v.w);
    dst[i] = o;
  }
}

__global__ void k_cast_pad(const float* __restrict__ src, u16* __restrict__ dst) {
  int i = blockIdx.x * 256 + threadIdx.x;
  int row = i >> 8;
  int c4 = (i & 255) * 4;
  if (row >= NPAD) return;
  ushort4 o;
  if (row < VV) {
    float4 v = *(const float4*)(src + (long)row * 1024 + c4);
    o.x = f2bf(v.x); o.y = f2bf(v.y); o.z = f2bf(v.z); o.w = f2bf(v.w);
  } else {
    o.x = 0; o.y = 0; o.z = 0; o.w = 0;
  }
  *(ushort4*)(dst + (long)row * 1024 + c4) = o;
}

__global__ void k_embed(const int* __restrict__ seq, const float* __restrict__ emb,
                        u16* __restrict__ x) {
  int rb = blockIdx.x;
  int v = seq[rb];
  const float4* s = (const float4*)(emb + (long)v * EE);
  ushort4* d = (ushort4*)(x + (long)rb * EE);
  int t = threadIdx.x;
  float4 val = s[t];
  ushort4 o;
  o.x = f2bf(val.x); o.y = f2bf(val.y); o.z = f2bf(val.z); o.w = f2bf(val.w);
  d[t] = o;
}

// ---------------- GEMM: C[M,N] = A[M,K] * B[N,K]^T + bias ----------------
template<int OUTF32>
__global__ __launch_bounds__(256) void k_gemm(
    const u16* __restrict__ A, const u16* __restrict__ B,
    const float* __restrict__ bias, void* __restrict__ C,
    int lda, int ldb, int ldc, int K, int ncols)
{
  __shared__ char smem[32768];
  const int tid = threadIdx.x;
  const int l = tid & 63;
  const int w = tid >> 6;
  const int wr = w >> 1, wc = w & 1;
  const long tM = (long)blockIdx.x * 128;
  const long tN = (long)blockIdx.y * 128;

  f32x4 acc[4][4];
#pragma unroll
  for (int m = 0; m < 4; m++)
#pragma unroll
    for (int n = 0; n < 4; n++) acc[m][n] = {0.f, 0.f, 0.f, 0.f};

  const int nk = K >> 6;
  for (int kt = 0; kt < nk; ++kt) {
    const int k0 = kt << 6;
#pragma unroll
    for (int t = 0; t < 4; t++) {
      int c2 = t * 256 + tid;
      int row = c2 >> 3, k8 = c2 & 7;
      uint4 va = *(const uint4*)(A + (tM + row) * lda + k0 + k8 * 8);
      int off = row * 128 + ((k8 * 16) ^ ((row & 7) << 4));
      *(uint4*)(smem + off) = va;
      uint4 vb = *(const uint4*)(B + (tN + row) * ldb + k0 + k8 * 8);
      *(uint4*)(smem + 16384 + off) = vb;
    }
    __syncthreads();
#pragma unroll
    for (int kk = 0; kk < 2; kk++) {
      const int kb = kk * 64 + ((l >> 4) * 16);
      bf16x8 af[4], bfr[4];
#pragma unroll
      for (int m = 0; m < 4; m++) {
        int ra = wr * 64 + m * 16 + (l & 15);
        af[m] = *(const bf16x8*)(smem + ra * 128 + (kb ^ ((l & 7) << 4)));
      }
#pragma unroll
      for (int n = 0; n < 4; n++) {
        int rb2 = wc * 64 + n * 16 + (l & 15);
        bfr[n] = *(const bf16x8*)(smem + 16384 + rb2 * 128 + (kb ^ ((l & 7) << 4)));
      }
#pragma unroll
      for (int m = 0; m < 4; m++)
#pragma unroll
        for (int n = 0; n < 4; n++)
          acc[m][n] = __builtin_amdgcn_mfma_f32_16x16x32_bf16(af[m], bfr[n], acc[m][n], 0, 0, 0);
    }
    __syncthreads();
  }
#pragma unroll
  for (int n = 0; n < 4; n++) {
    long col = tN + wc * 64 + n * 16 + (l & 15);
    float bv = (col < ncols) ? bias[col] : 0.f;
    if (col < ncols) {
#pragma unroll
      for (int m = 0; m < 4; m++) {
        long row = tM + wr * 64 + m * 16 + ((l >> 4) * 4);
#pragma unroll
        for (int r = 0; r < 4; r++) {
          float v = acc[m][n][r] + bv;
          if (OUTF32) ((float*)C)[(row + r) * ldc + col] = v;
          else        ((u16*)C)[(row + r) * ldc + col] = f2bf(v);
        }
      }
    }
  }
}

// ---------------- GRU: one phase (one direction, one step) ----------------
// DIR compile-time so hreg/bh stay in registers (no runtime indexing).
template<int DIR>
static __device__ __forceinline__ void gru_phase(
    int blk, int tid, int t, bool do_poll, bool do_post, int post_dir, int post_t,
    const u16* __restrict__ gx,        // gx base for this direction
    u16* __restrict__ hsteps, u16* __restrict__ cat, int* __restrict__ bar,
    const char* __restrict__ Wd,       // LDS W slice for this direction
    u16 (*hstage)[CC],
    const float* bh, float* hreg)
{
  const int l = tid & 63, w = tid >> 6;
  const int lrow = w * 16 + ((l >> 4) * 4);
  const int lpos = DIR ? (LL - 1 - t) : t;

  // gx loads issued BEFORE the poll: HBM latency rides the poll round trip
  u16 gxv[3][4];
#pragma unroll
  for (int r = 0; r < 4; r++) {
    const u16* gxr = gx + ((long)lpos * BB + (lrow + r)) * G3 + blk * CC + (l & 15);
#pragma unroll
    for (int g = 0; g < 3; g++) gxv[g][r] = gxr[g * HH];
  }

  // poll producer flags for h(t) (posted ~one phase ago -> usually 1 RT)
  if (do_poll) {
    const int* flg = bar + (DIR * LL + t) * NB;
    for (;;) {
      int v = 1;
      if (l < NB) v = flagload4(&flg[l]);
      if (__all(v != 0)) break;
    }
  }

  // h tile load (plain cached; per-step buffer is fresh by construction)
  const u16* hsrc = hsteps + ((size_t)t * 2 + DIR) * BB * HH;
  bf16x8 af[16];
  {
    const u16* hrow = hsrc + (w * 16 + (l & 15)) * HH + ((l >> 4) * 8);
#pragma unroll
    for (int kc = 0; kc < 16; kc++) af[kc] = *(const bf16x8*)(hrow + kc * 32);
  }
  asm volatile("s_waitcnt vmcnt(0)" ::: "memory");   // af ready; also acks the
  __syncthreads();                                   // OTHER chain's h stores
  if (do_post && tid == 0)
    flagstore4(&bar[(post_dir * LL + post_t) * NB + blk], 1);
  __builtin_amdgcn_sched_barrier(0);

  // MFMA: gh[64 x 48] = h[64x512] @ Wslice^T
  f32x4 acc[3];
#pragma unroll
  for (int g = 0; g < 3; g++) acc[g] = {0.f, 0.f, 0.f, 0.f};
#pragma unroll
  for (int kc = 0; kc < 16; kc++) {
    const int kb = kc * 64 + ((l >> 4) * 16);
#pragma unroll
    for (int g = 0; g < 3; g++) {
      int lr = g * 16 + (l & 15);
      bf16x8 bfr = *(const bf16x8*)(Wd + lr * 1024 + (kb ^ ((l & 7) << 4)));
      acc[g] = __builtin_amdgcn_mfma_f32_16x16x32_bf16(af[kc], bfr, acc[g], 0, 0, 0);
    }
  }

  // gates -> hstage
#pragma unroll
  for (int r = 0; r < 4; r++) {
    float ghr = acc[0][r] + bh[0];
    float ghz = acc[1][r] + bh[1];
    float ghn = acc[2][r] + bh[2];
    float xr = bf2f(gxv[0][r]);
    float xz = bf2f(gxv[1][r]);
    float xn = bf2f(gxv[2][r]);
    float ar = fminf(fmaxf(xr + ghr, -30.f), 30.f);
    float az = fminf(fmaxf(xz + ghz, -30.f), 30.f);
    float rg = 1.f / (1.f + __expf(-ar));
    float zg = 1.f / (1.f + __expf(-az));
    float an = fminf(fmaxf(xn + rg * ghn, -30.f), 30.f);
    float e2 = __expf(-2.f * an);
    float ng = (1.f - e2) / (1.f + e2);
    float hn = (1.f - zg) * ng + zg * hreg[r];
    hreg[r] = hn;
    hstage[lrow + r][l & 15] = f2bf(hn);
  }
  __syncthreads();

  // issue h stores (sc0 sc1) + cat stores; ack happens in the NEXT phase
  if (tid < 128) {
    const int srow = tid >> 1, ch = tid & 1;
    u32x4 hv = *(const u32x4*)&hstage[srow][ch * 8];
    if (t < LL - 1)
      cstore16(hsteps + ((size_t)(t + 1) * 2 + DIR) * BB * HH + srow * HH + blk * CC + ch * 8, hv);
    if (DIR == 0) {
      if (lpos < LL - 2)
        *(u32x4*)(cat + ((long)lpos * BB + srow) * D2H + blk * CC + ch * 8) = hv;
    } else {
      if (lpos >= 2)
        *(u32x4*)(cat + ((long)(lpos - 2) * BB + srow) * D2H + HH + blk * CC + ch * 8) = hv;
    }
  }
}

// ---------------- GRU kernel: both directions interleaved per block ----------
// 32 blocks; block owns hidden cols [blk*16, blk*16+16) of BOTH directions.
// W slices (2 x 48KB) LDS-resident. Phase schedule per iteration t:
//   F(t): poll f[t]; compute fwd; (vmcnt acks h_b(t) stores) post b[t]; store h_f(t+1)
//   B(t): poll b[t]; compute bwd; (vmcnt acks h_f(t+1) stores) post f[t+1]; store h_b(t+1)
// Each chain's sync latency hides under the other chain's compute.
__global__ __launch_bounds__(256) void k_gru(
    const u16* __restrict__ Whh_all,   // [2][1536][512] bf16
    const float* __restrict__ bhh_f, const float* __restrict__ bhh_b,
    const u16* __restrict__ gx_all,    // [2][8192][1536] bf16
    u16* __restrict__ hsteps,          // [129][2][64][512] bf16
    u16* __restrict__ cat,             // [8064][1024] bf16
    int* __restrict__ bar)             // [2][128][32]
{
  const int blk = blockIdx.x;
  const int tid = threadIdx.x;
  const int l = tid & 63;

  __shared__ char Wl[2][48 * 1024];            // 96KB: both dirs' W slices
  __shared__ __align__(16) u16 hstage[BB][CC]; // 2KB repack tile

  // stage W slices (48 rows x 512 bf16 each, swizzled)
#pragma unroll
  for (int d = 0; d < 2; d++) {
    for (int c = tid; c < 3072; c += 256) {
      int lr = c >> 6, k8 = c & 63;
      int gr = (lr >> 4) * HH + blk * CC + (lr & 15);
      uint4 v = *(const uint4*)(Whh_all + ((long)d * G3 + gr) * HH + k8 * 8);
      *(uint4*)(Wl[d] + lr * 1024 + ((k8 * 16) ^ ((lr & 7) << 4))) = v;
    }
  }
  float bhf[3], bhb[3];
#pragma unroll
  for (int g = 0; g < 3; g++) {
    bhf[g] = bhh_f[g * HH + blk * CC + (l & 15)];
    bhb[g] = bhh_b[g * HH + blk * CC + (l & 15)];
  }
  float hreg_f[4] = {}, hreg_b[4] = {};
  __syncthreads();

  const u16* gx_f = gx_all;
  const u16* gx_b = gx_all + (size_t)MROWS * G3;

  for (int t = 0; t < LL; ++t) {
    // F(t): posts flags_b[t] (h_b(t) stores from B(t-1) ack'd by our vmcnt)
    gru_phase<0>(blk, tid, t, /*poll*/ t > 0, /*post*/ t > 0, 1, t,
                 gx_f, hsteps, cat, bar, Wl[0], hstage, bhf, hreg_f);
    // B(t): posts flags_f[t+1] (h_f(t+1) stores from F(t) ack'd by our vmcnt)
    gru_phase<1>(blk, tid, t, /*poll*/ t > 0, /*post*/ t < LL - 1, 0, t + 1,
                 gx_b, hsteps, cat, bar, Wl[1], hstage, bhb, hreg_b);
  }
}

// ---------------- log-softmax over V=10000 per row ----------------
__global__ __launch_bounds__(256) void k_lsm(float* __restrict__ out) {
  const long row = blockIdx.x;
  float* p = out + row * VV;
  const int tid = threadIdx.x;
  const int l = tid & 63, w = tid >> 6;
  __shared__ float red[8];

  float4 v[10];
  float m = -1e30f;
#pragma unroll
  for (int j = 0; j < 10; j++) {
    int idx = j * 256 + tid;
    if (idx < 2500) {
      v[j] = *(float4*)(p + idx * 4);
      m = fmaxf(m, fmaxf(fmaxf(v[j].x, v[j].y), fmaxf(v[j].z, v[j].w)));
    }
  }
#pragma unroll
  for (int off = 32; off; off >>= 1) m = fmaxf(m, __shfl_xor(m, off));
  if (l == 0) red[w] = m;
  __syncthreads();
  m = fmaxf(fmaxf(red[0], red[1]), fmaxf(red[2], red[3]));

  float s = 0.f;
#pragma unroll
  for (int j = 0; j < 10; j++) {
    int idx = j * 256 + tid;
    if (idx < 2500) {
      s += __expf(v[j].x - m) + __expf(v[j].y - m) + __expf(v[j].z - m) + __expf(v[j].w - m);
    }
  }
#pragma unroll
  for (int off = 32; off; off >>= 1) s += __shfl_xor(s, off);
  if (l == 0) red[4 + w] = s;
  __syncthreads();
  s = red[4] + red[5] + red[6] + red[7];
  float lse = m + logf(s);

#pragma unroll
  for (int j = 0; j < 10; j++) {
    int idx = j * 256 + tid;
    if (idx < 2500) {
      float4 o;
      o.x = v[j].x - lse; o.y = v[j].y - lse; o.z = v[j].z - lse; o.w = v[j].w - lse;
      *(float4*)(p + idx * 4) = o;
    }
  }
}

// ---------------- launch ----------------
extern "C" void kernel_launch(void* const* d_in, const int* in_sizes, int n_in,
                              void* d_out, int out_size, void* d_ws, size_t ws_size,
                              hipStream_t stream) {
  const int*   seq  = (const int*)d_in[0];
  const float* emb  = (const float*)d_in[2];
  const float* Wihf = (const float*)d_in[3];
  const float* Whhf = (const float*)d_in[4];
  const float* bihf = (const float*)d_in[5];
  const float* bhhf = (const float*)d_in[6];
  const float* Wihb = (const float*)d_in[7];
  const float* Whhb = (const float*)d_in[8];
  const float* bihb = (const float*)d_in[9];
  const float* bhhb = (const float*)d_in[10];
  const float* decW = (const float*)d_in[11];
  const float* decb = (const float*)d_in[12];

  char* ws = (char*)d_ws;
  size_t off = 0;
  u16* Whh_bf = (u16*)(ws + off); off += (size_t)2 * G3 * HH * 2;        // 3.1M
  u16* Wih_bf = (u16*)(ws + off); off += (size_t)2 * G3 * EE * 2;        // 3.1M
  u16* decW_bf = (u16*)(ws + off); off += (size_t)NPAD * D2H * 2;        // 20.7M
  u16* xb = (u16*)(ws + off); off += (size_t)MROWS * EE * 2;             // 8.4M
  u16* gxb = (u16*)(ws + off); off += (size_t)2 * MROWS * G3 * 2;        // 50.3M
  u16* cat = (u16*)(ws + off); off += (size_t)DM * D2H * 2;              // 16.5M
  u16* hsteps = (u16*)(ws + off); off += (size_t)(LL + 1) * 2 * BB * HH * 2; // 16.9M
  int* bar = (int*)(ws + off); off += (size_t)2 * LL * NB * 4;           // 32K

  // zero hstep[0] (both dirs) + flags — every call so replays reset
  (void)hipMemsetAsync(hsteps, 0, (size_t)2 * BB * HH * 2, stream);
  (void)hipMemsetAsync(bar, 0, (size_t)2 * LL * NB * 4, stream);

  const int n4w = G3 * HH / 4;
  k_cast<<<(n4w + 255) / 256, 256, 0, stream>>>((const float4*)Whhf, (ushort4*)(Whh_bf), n4w);
  k_cast<<<(n4w + 255) / 256, 256, 0, stream>>>((const float4*)Whhb, (ushort4*)(Whh_bf + G3 * HH), n4w);
  k_cast<<<(n4w + 255) / 256, 256, 0, stream>>>((const float4*)Wihf, (ushort4*)(Wih_bf), n4w);
  k_cast<<<(n4w + 255) / 256, 256, 0, stream>>>((const float4*)Wihb, (ushort4*)(Wih_bf + G3 * EE), n4w);
  k_cast_pad<<<NPAD, 256, 0, stream>>>(decW, decW_bf);
  k_embed<<<MROWS, 128, 0, stream>>>(seq, emb, xb);

  k_gemm<0><<<dim3(64, 12), 256, 0, stream>>>(xb, Wih_bf, bihf, gxb, EE, EE, G3, EE, G3);
  k_gemm<0><<<dim3(64, 12), 256, 0, stream>>>(xb, Wih_bf + G3 * EE, bihb, gxb + (size_t)MROWS * G3, EE, EE, G3, EE, G3);

  k_gru<<<dim3(NB), 256, 0, stream>>>(Whh_bf, bhhf, bhhb, gxb, hsteps, cat, bar);

  k_gemm<1><<<dim3(63, 79), 256, 0, stream>>>(cat, decW_bf, decb, d_out, D2H, D2H, VV, D2H, VV);

  k_lsm<<<DM, 256, 0, stream>>>((float*)d_out);
}

// Round 11
// 1317.558 us; speedup vs baseline: 1.1840x; 1.1840x over previous
//
#include <hip/hip_runtime.h>
#include <hip/hip_bf16.h>
#include <stdint.h>

#define LL 128
#define BB 64
#define VV 10000
#define EE 512
#define HH 512
#define G3 1536
#define MROWS 8192      // L*B
#define DM 8064         // (L-2)*B
#define D2H 1024
#define NPAD 10112      // 79*128
#define FP 16           // flag padding (ints) -> one 64B line per producer

typedef __bf16 bf16x8 __attribute__((ext_vector_type(8)));
typedef float f32x4 __attribute__((ext_vector_type(4)));
typedef unsigned int u32x4 __attribute__((ext_vector_type(4)));
typedef unsigned short u16;

static __device__ __forceinline__ float bf2f(u16 u) {
  unsigned int x = ((unsigned int)u) << 16;
  return __builtin_bit_cast(float, x);
}
static __device__ __forceinline__ u16 f2bf(float f) {
  unsigned int x = __builtin_bit_cast(unsigned int, f);
  unsigned int r = x + 0x7FFFu + ((x >> 16) & 1u);
  return (u16)(r >> 16);
}

// device-coherent (L1+L2-bypassing, visible at L3) ops — producers/flags only
static __device__ __forceinline__ void cstore16(void* p, u32x4 v) {
  asm volatile("global_store_dwordx4 %0, %1, off sc0 sc1" :: "v"(p), "v"(v) : "memory");
}
static __device__ __forceinline__ void flagstore4(void* p, int v) {
  asm volatile("global_store_dword %0, %1, off sc0 sc1" :: "v"(p), "v"(v) : "memory");
}
static __device__ __forceinline__ int flagload4(const void* p) {
  int v;
  asm volatile("global_load_dword %0, %1, off sc0 sc1\n\ts_waitcnt vmcnt(0)"
               : "=v"(v) : "v"(p) : "memory");
  return v;
}
// async global->LDS, 16B per lane: LDS dest = wave-uniform base + lane*16
static __device__ __forceinline__ void gload_lds16(const void* g, void* s) {
  __builtin_amdgcn_global_load_lds(
      (const __attribute__((address_space(1))) unsigned int*)g,
      (__attribute__((address_space(3))) unsigned int*)s, 16, 0, 0);
}

// ---------------- cast kernels ----------------
__global__ void k_cast(const float4* __restrict__ src, ushort4* __restrict__ dst, int n4) {
  int i = blockIdx.x * blockDim.x + threadIdx.x;
  if (i < n4) {
    float4 v = src[i];
    ushort4 o;
    o.x = f2bf(v.x); o.y = f2bf(v.y); o.z = f2bf(v.z); o.w = f2bf(v.w);
    dst[i] = o;
  }
}

__global__ void k_cast_pad(const float* __restrict__ src, u16* __restrict__ dst) {
  int i = blockIdx.x * 256 + threadIdx.x;
  int row = i >> 8;
  int c4 = (i & 255) * 4;
  if (row >= NPAD) return;
  ushort4 o;
  if (row < VV) {
    float4 v = *(const float4*)(src + (long)row * 1024 + c4);
    o.x = f2bf(v.x); o.y = f2bf(v.y); o.z = f2bf(v.z); o.w = f2bf(v.w);
  } else {
    o.x = 0; o.y = 0; o.z = 0; o.w = 0;
  }
  *(ushort4*)(dst + (long)row * 1024 + c4) = o;
}

__global__ void k_embed(const int* __restrict__ seq, const float* __restrict__ emb,
                        u16* __restrict__ x) {
  int rb = blockIdx.x;
  int v = seq[rb];
  const float4* s = (const float4*)(emb + (long)v * EE);
  ushort4* d = (ushort4*)(x + (long)rb * EE);
  int t = threadIdx.x;
  float4 val = s[t];
  ushort4 o;
  o.x = f2bf(val.x); o.y = f2bf(val.y); o.z = f2bf(val.z); o.w = f2bf(val.w);
  d[t] = o;
}

// ---------------- GEMM: C[M,N] = A[M,K] * B[N,K]^T + bias ----------------
// m97-style: global_load_lds width-16 staging into LINEAR LDS tiles.
template<int OUTF32>
__global__ __launch_bounds__(256) void k_gemm(
    const u16* __restrict__ A, const u16* __restrict__ B,
    const float* __restrict__ bias, void* __restrict__ C,
    int lda, int ldb, int ldc, int K, int ncols)
{
  __shared__ char smem[32768];      // A tile 16KB (linear [128][64]) + B tile 16KB
  const int tid = threadIdx.x;
  const int l = tid & 63;
  const int w = tid >> 6;
  const int wr = w >> 1, wc = w & 1;
  const long tM = (long)blockIdx.x * 128;
  const long tN = (long)blockIdx.y * 128;

  f32x4 acc[4][4];
#pragma unroll
  for (int m = 0; m < 4; m++)
#pragma unroll
    for (int n = 0; n < 4; n++) acc[m][n] = {0.f, 0.f, 0.f, 0.f};

  const int nk = K >> 6;
  for (int kt = 0; kt < nk; ++kt) {
    const int k0 = kt << 6;
    // stage A+B: each wave issues 4 chunks per tile; chunk = 64 lanes x 16B
#pragma unroll
    for (int i = 0; i < 4; i++) {
      int cchunk = w * 4 + i;             // 0..15
      int c = cchunk * 64 + l;            // 16B unit index: row = c>>3, k8 = c&7
      int row = c >> 3, k8 = c & 7;
      gload_lds16(A + (tM + row) * lda + k0 + k8 * 8, smem + cchunk * 1024);
      gload_lds16(B + (tN + row) * ldb + k0 + k8 * 8, smem + 16384 + cchunk * 1024);
    }
    __syncthreads();
#pragma unroll
    for (int kk = 0; kk < 2; kk++) {
      const int kb = kk * 64 + ((l >> 4) * 16);   // byte offset in row (0..127)
      bf16x8 af[4], bfr[4];
#pragma unroll
      for (int m = 0; m < 4; m++) {
        int ra = wr * 64 + m * 16 + (l & 15);
        af[m] = *(const bf16x8*)(smem + ra * 128 + kb);
      }
#pragma unroll
      for (int n = 0; n < 4; n++) {
        int rb2 = wc * 64 + n * 16 + (l & 15);
        bfr[n] = *(const bf16x8*)(smem + 16384 + rb2 * 128 + kb);
      }
#pragma unroll
      for (int m = 0; m < 4; m++)
#pragma unroll
        for (int n = 0; n < 4; n++)
          acc[m][n] = __builtin_amdgcn_mfma_f32_16x16x32_bf16(af[m], bfr[n], acc[m][n], 0, 0, 0);
    }
    __syncthreads();
  }
#pragma unroll
  for (int n = 0; n < 4; n++) {
    long col = tN + wc * 64 + n * 16 + (l & 15);
    float bv = (col < ncols) ? bias[col] : 0.f;
    if (col < ncols) {
#pragma unroll
      for (int m = 0; m < 4; m++) {
        long row = tM + wr * 64 + m * 16 + ((l >> 4) * 4);
#pragma unroll
        for (int r = 0; r < 4; r++) {
          float v = acc[m][n][r] + bv;
          if (OUTF32) ((float*)C)[(row + r) * ldc + col] = v;
          else        ((u16*)C)[(row + r) * ldc + col] = f2bf(v);
        }
      }
    }
  }
}

// ---------------- GRU recurrence (Round-8 proven structure) ----------------
// grid (16, 2): block owns hidden cols [blk*32, blk*32+32); W_hh slice in LDS.
// h exchange via per-step buffers hstep[t][dir]; producers sc0 sc1 + ack + flag
// (flags padded to one 64B line each); consumers plain cached loads.
__global__ __launch_bounds__(256) void k_gru(
    const u16* __restrict__ Whh_all,   // [2][1536][512] bf16
    const float* __restrict__ bhh_f, const float* __restrict__ bhh_b,
    const u16* __restrict__ gx_all,    // [2][8192][1536] bf16
    u16* __restrict__ hsteps,          // [129][2][64][512] bf16
    u16* __restrict__ cat,             // [8064][1024] bf16
    int* __restrict__ bar16)           // [2][128][16][FP]
{
  const int blk = blockIdx.x;
  const int dir = blockIdx.y;
  const int tid = threadIdx.x;
  const int l = tid & 63, w = tid >> 6;
  const u16* Whh = Whh_all + (long)dir * G3 * HH;
  const float* bhh = dir ? bhh_b : bhh_f;
  const u16* gx = gx_all + (long)dir * MROWS * G3;

  __shared__ char Wl[96 * 1024];               // 96 rows x 512 bf16, swizzled
  __shared__ __align__(16) u16 hstage[BB][32]; // 4KB repack tile

  for (int c = tid; c < 6144; c += 256) {
    int lr = c >> 6;
    int k8 = c & 63;
    int gr = (lr >> 5) * HH + blk * 32 + (lr & 31);
    uint4 v = *(const uint4*)(Whh + (long)gr * HH + k8 * 8);
    *(uint4*)(Wl + lr * 1024 + ((k8 * 16) ^ ((lr & 7) << 4))) = v;
  }
  float bh[6];
#pragma unroll
  for (int n = 0; n < 6; n++) {
    int c = n * 16 + (l & 15);
    bh[n] = bhh[(c >> 5) * HH + blk * 32 + (c & 31)];
  }
  float hreg[4][2] = {};
  __syncthreads();

  const int lrow = w * 16 + ((l >> 4) * 4);
  const int srow = tid >> 2, schunk = tid & 3;

  for (int t = 0; t < LL; ++t) {
    const int lpos = dir ? (LL - 1 - t) : t;
    const u16* hsrc = hsteps + ((size_t)t * 2 + dir) * BB * HH;

    bf16x8 af[16];
    {
      const u16* hrow = hsrc + (w * 16 + (l & 15)) * HH + ((l >> 4) * 8);
#pragma unroll
      for (int kc = 0; kc < 16; kc++) af[kc] = *(const bf16x8*)(hrow + kc * 32);
    }
    u16 gxv[3][4][2];
#pragma unroll
    for (int r = 0; r < 4; r++) {
      const u16* gxr = gx + ((long)lpos * BB + (lrow + r)) * G3 + blk * 32;
#pragma unroll
      for (int g = 0; g < 3; g++)
#pragma unroll
        for (int p = 0; p < 2; p++)
          gxv[g][r][p] = gxr[g * HH + p * 16 + (l & 15)];
    }

    f32x4 acc[6];
#pragma unroll
    for (int n = 0; n < 6; n++) acc[n] = {0.f, 0.f, 0.f, 0.f};
#pragma unroll
    for (int kc = 0; kc < 16; kc++) {
      const int kb = kc * 64 + ((l >> 4) * 16);
#pragma unroll
      for (int n = 0; n < 6; n++) {
        int lr = n * 16 + (l & 15);
        bf16x8 bfr = *(const bf16x8*)(Wl + lr * 1024 + (kb ^ ((l & 7) << 4)));
        acc[n] = __builtin_amdgcn_mfma_f32_16x16x32_bf16(af[kc], bfr, acc[n], 0, 0, 0);
      }
    }

#pragma unroll
    for (int r = 0; r < 4; r++) {
#pragma unroll
      for (int p = 0; p < 2; p++) {
        float ghr = acc[0 + p][r] + bh[0 + p];
        float ghz = acc[2 + p][r] + bh[2 + p];
        float ghn = acc[4 + p][r] + bh[4 + p];
        float xr = bf2f(gxv[0][r][p]);
        float xz = bf2f(gxv[1][r][p]);
        float xn = bf2f(gxv[2][r][p]);
        float ar = fminf(fmaxf(xr + ghr, -30.f), 30.f);
        float az = fminf(fmaxf(xz + ghz, -30.f), 30.f);
        float rg = 1.f / (1.f + __expf(-ar));
        float zg = 1.f / (1.f + __expf(-az));
        float an = fminf(fmaxf(xn + rg * ghn, -30.f), 30.f);
        float e2 = __expf(-2.f * an);
        float ng = (1.f - e2) / (1.f + e2);
        float hn = (1.f - zg) * ng + zg * hreg[r][p];
        hreg[r][p] = hn;
        hstage[lrow + r][p * 16 + (l & 15)] = f2bf(hn);
      }
    }
    __syncthreads();

    u32x4 hv = *(const u32x4*)&hstage[srow][schunk * 8];
    if (t < LL - 1) {
      u16* hdst = hsteps + ((size_t)(t + 1) * 2 + dir) * BB * HH;
      cstore16(hdst + srow * HH + blk * 32 + schunk * 8, hv);
      asm volatile("s_waitcnt vmcnt(0)" ::: "memory");
      __syncthreads();
      if (tid == 0)
        flagstore4(&bar16[((dir * LL + t) * 16 + blk) * FP], 1);
      const int* flg = bar16 + (dir * LL + t) * 16 * FP;
      for (;;) {
        int v = 1;
        if (l < 16) v = flagload4(&flg[l * FP]);
        if (__all(v != 0)) break;
      }
      __builtin_amdgcn_sched_barrier(0);
    }
    if (dir == 0) {
      if (lpos < LL - 2)
        *(u32x4*)(cat + ((long)lpos * BB + srow) * D2H + blk * 32 + schunk * 8) = hv;
    } else {
      if (lpos >= 2)
        *(u32x4*)(cat + ((long)(lpos - 2) * BB + srow) * D2H + HH + blk * 32 + schunk * 8) = hv;
    }
  }
}

// ---------------- log-softmax over V=10000 per row ----------------
__global__ __launch_bounds__(256) void k_lsm(float* __restrict__ out) {
  const long row = blockIdx.x;
  float* p = out + row * VV;
  const int tid = threadIdx.x;
  const int l = tid & 63, w = tid >> 6;
  __shared__ float red[8];

  float4 v[10];
  float m = -1e30f;
#pragma unroll
  for (int j = 0; j < 10; j++) {
    int idx = j * 256 + tid;
    if (idx < 2500) {
      v[j] = *(float4*)(p + idx * 4);
      m = fmaxf(m, fmaxf(fmaxf(v[j].x, v[j].y), fmaxf(v[j].z, v[j].w)));
    }
  }
#pragma unroll
  for (int off = 32; off; off >>= 1) m = fmaxf(m, __shfl_xor(m, off));
  if (l == 0) red[w] = m;
  __syncthreads();
  m = fmaxf(fmaxf(red[0], red[1]), fmaxf(red[2], red[3]));

  float s = 0.f;
#pragma unroll
  for (int j = 0; j < 10; j++) {
    int idx = j * 256 + tid;
    if (idx < 2500) {
      s += __expf(v[j].x - m) + __expf(v[j].y - m) + __expf(v[j].z - m) + __expf(v[j].w - m);
    }
  }
#pragma unroll
  for (int off = 32; off; off >>= 1) s += __shfl_xor(s, off);
  if (l == 0) red[4 + w] = s;
  __syncthreads();
  s = red[4] + red[5] + red[6] + red[7];
  float lse = m + logf(s);

#pragma unroll
  for (int j = 0; j < 10; j++) {
    int idx = j * 256 + tid;
    if (idx < 2500) {
      float4 o;
      o.x = v[j].x - lse; o.y = v[j].y - lse; o.z = v[j].z - lse; o.w = v[j].w - lse;
      *(float4*)(p + idx * 4) = o;
    }
  }
}

// ---------------- launch ----------------
extern "C" void kernel_launch(void* const* d_in, const int* in_sizes, int n_in,
                              void* d_out, int out_size, void* d_ws, size_t ws_size,
                              hipStream_t stream) {
  const int*   seq  = (const int*)d_in[0];
  const float* emb  = (const float*)d_in[2];
  const float* Wihf = (const float*)d_in[3];
  const float* Whhf = (const float*)d_in[4];
  const float* bihf = (const float*)d_in[5];
  const float* bhhf = (const float*)d_in[6];
  const float* Wihb = (const float*)d_in[7];
  const float* Whhb = (const float*)d_in[8];
  const float* bihb = (const float*)d_in[9];
  const float* bhhb = (const float*)d_in[10];
  const float* decW = (const float*)d_in[11];
  const float* decb = (const float*)d_in[12];

  char* ws = (char*)d_ws;
  size_t off = 0;
  u16* Whh_bf = (u16*)(ws + off); off += (size_t)2 * G3 * HH * 2;        // 3.1M
  u16* Wih_bf = (u16*)(ws + off); off += (size_t)2 * G3 * EE * 2;        // 3.1M
  u16* decW_bf = (u16*)(ws + off); off += (size_t)NPAD * D2H * 2;        // 20.7M
  u16* xb = (u16*)(ws + off); off += (size_t)MROWS * EE * 2;             // 8.4M
  u16* gxb = (u16*)(ws + off); off += (size_t)2 * MROWS * G3 * 2;        // 50.3M
  u16* cat = (u16*)(ws + off); off += (size_t)DM * D2H * 2;              // 16.5M
  u16* hsteps = (u16*)(ws + off); off += (size_t)(LL + 1) * 2 * BB * HH * 2; // 16.9M
  int* bar16 = (int*)(ws + off); off += (size_t)2 * LL * 16 * FP * 4;    // 2M

  // zero hstep[0] (both dirs) + flags — every call so replays reset
  (void)hipMemsetAsync(hsteps, 0, (size_t)2 * BB * HH * 2, stream);
  (void)hipMemsetAsync(bar16, 0, (size_t)2 * LL * 16 * FP * 4, stream);

  const int n4w = G3 * HH / 4;
  k_cast<<<(n4w + 255) / 256, 256, 0, stream>>>((const float4*)Whhf, (ushort4*)(Whh_bf), n4w);
  k_cast<<<(n4w + 255) / 256, 256, 0, stream>>>((const float4*)Whhb, (ushort4*)(Whh_bf + G3 * HH), n4w);
  k_cast<<<(n4w + 255) / 256, 256, 0, stream>>>((const float4*)Wihf, (ushort4*)(Wih_bf), n4w);
  k_cast<<<(n4w + 255) / 256, 256, 0, stream>>>((const float4*)Wihb, (ushort4*)(Wih_bf + G3 * EE), n4w);
  k_cast_pad<<<NPAD, 256, 0, stream>>>(decW, decW_bf);
  k_embed<<<MROWS, 128, 0, stream>>>(seq, emb, xb);

  k_gemm<0><<<dim3(64, 12), 256, 0, stream>>>(xb, Wih_bf, bihf, gxb, EE, EE, G3, EE, G3);
  k_gemm<0><<<dim3(64, 12), 256, 0, stream>>>(xb, Wih_bf + G3 * EE, bihb, gxb + (size_t)MROWS * G3, EE, EE, G3, EE, G3);

  k_gru<<<dim3(16, 2), 256, 0, stream>>>(Whh_bf, bhhf, bhhb, gxb, hsteps, cat, bar16);

  k_gemm<1><<<dim3(63, 79), 256, 0, stream>>>(cat, decW_bf, decb, d_out, D2H, D2H, VV, D2H, VV);

  k_lsm<<<DM, 256, 0, stream>>>((float*)d_out);
}

// Round 12
// 1212.275 us; speedup vs baseline: 1.2868x; 1.0868x over previous
//
#include <hip/hip_runtime.h>
#include <hip/hip_bf16.h>
#include <stdint.h>

#define LL 128
#define BB 64
#define VV 10000
#define EE 512
#define HH 512
#define G3 1536
#define MROWS 8192      // L*B
#define DM 8064         // (L-2)*B
#define D2H 1024
#define NPAD 10112      // 79*128
#define FP 16           // flag padding (ints) -> one 64B line per producer

typedef __bf16 bf16x8 __attribute__((ext_vector_type(8)));
typedef float f32x4 __attribute__((ext_vector_type(4)));
typedef int i32x4 __attribute__((ext_vector_type(4)));
typedef unsigned int u32x4 __attribute__((ext_vector_type(4)));
typedef unsigned short u16;

static __device__ __forceinline__ float bf2f(u16 u) {
  unsigned int x = ((unsigned int)u) << 16;
  return __builtin_bit_cast(float, x);
}
static __device__ __forceinline__ u16 f2bf(float f) {
  unsigned int x = __builtin_bit_cast(unsigned int, f);
  unsigned int r = x + 0x7FFFu + ((x >> 16) & 1u);
  return (u16)(r >> 16);
}
static __device__ __forceinline__ signed char q8(float v) {
  float r = fminf(fmaxf(rintf(v), -127.f), 127.f);
  return (signed char)(int)r;
}

// device-coherent (L1+L2-bypassing, visible at L3) ops — producers/flags only
static __device__ __forceinline__ void cstore16(void* p, u32x4 v) {
  asm volatile("global_store_dwordx4 %0, %1, off sc0 sc1" :: "v"(p), "v"(v) : "memory");
}
static __device__ __forceinline__ void flagstore4(void* p, int v) {
  asm volatile("global_store_dword %0, %1, off sc0 sc1" :: "v"(p), "v"(v) : "memory");
}
static __device__ __forceinline__ int flagload4(const void* p) {
  int v;
  asm volatile("global_load_dword %0, %1, off sc0 sc1\n\ts_waitcnt vmcnt(0)"
               : "=v"(v) : "v"(p) : "memory");
  return v;
}
// async global->LDS, 16B per lane: LDS dest = wave-uniform base + lane*16
static __device__ __forceinline__ void gload_lds16(const void* g, void* s) {
  __builtin_amdgcn_global_load_lds(
      (const __attribute__((address_space(1))) unsigned int*)g,
      (__attribute__((address_space(3))) unsigned int*)s, 16, 0, 0);
}

// ---------------- cast / quant kernels ----------------
__global__ void k_cast(const float4* __restrict__ src, ushort4* __restrict__ dst, int n4) {
  int i = blockIdx.x * blockDim.x + threadIdx.x;
  if (i < n4) {
    float4 v = src[i];
    ushort4 o;
    o.x = f2bf(v.x); o.y = f2bf(v.y); o.z = f2bf(v.z); o.w = f2bf(v.w);
    dst[i] = o;
  }
}

// decW [VV][1024] f32 -> per-row-scaled i8 + wscale[v] = rowmax/(127*127)
__global__ __launch_bounds__(256) void k_quant_w(const float* __restrict__ W,
                                                 signed char* __restrict__ Q,
                                                 float* __restrict__ wscale) {
  const int v = blockIdx.x;
  const int tid = threadIdx.x;
  const int l = tid & 63, w = tid >> 6;
  float4 x = *(const float4*)(W + (long)v * 1024 + tid * 4);
  float m = fmaxf(fmaxf(fabsf(x.x), fabsf(x.y)), fmaxf(fabsf(x.z), fabsf(x.w)));
#pragma unroll
  for (int off = 32; off; off >>= 1) m = fmaxf(m, __shfl_xor(m, off));
  __shared__ float red[4];
  __shared__ float s_inv;
  if (l == 0) red[w] = m;
  __syncthreads();
  if (tid == 0) {
    float mm = fmaxf(fmaxf(red[0], red[1]), fmaxf(red[2], red[3]));
    mm = fmaxf(mm, 1e-12f);
    s_inv = 127.f / mm;
    wscale[v] = mm / (127.f * 127.f);
  }
  __syncthreads();
  float inv = s_inv;
  char4 o;
  o.x = q8(x.x * inv); o.y = q8(x.y * inv); o.z = q8(x.z * inv); o.w = q8(x.w * inv);
  *(char4*)(Q + (long)v * 1024 + tid * 4) = o;
}

// cat bf16 -> i8 with fixed scale 127 (|h| < 1 guaranteed by GRU recurrence)
__global__ void k_quant_a(const u16* __restrict__ src, signed char* __restrict__ Q, int n4) {
  int i = blockIdx.x * 256 + threadIdx.x;
  if (i < n4) {
    ushort4 u = ((const ushort4*)src)[i];
    char4 o;
    o.x = q8(bf2f(u.x) * 127.f); o.y = q8(bf2f(u.y) * 127.f);
    o.z = q8(bf2f(u.z) * 127.f); o.w = q8(bf2f(u.w) * 127.f);
    ((char4*)Q)[i] = o;
  }
}

__global__ void k_embed(const int* __restrict__ seq, const float* __restrict__ emb,
                        u16* __restrict__ x) {
  int rb = blockIdx.x;
  int v = seq[rb];
  const float4* s = (const float4*)(emb + (long)v * EE);
  ushort4* d = (ushort4*)(x + (long)rb * EE);
  int t = threadIdx.x;
  float4 val = s[t];
  ushort4 o;
  o.x = f2bf(val.x); o.y = f2bf(val.y); o.z = f2bf(val.z); o.w = f2bf(val.w);
  d[t] = o;
}

// ---------------- bf16 GEMM (gx): C[M,N] = A[M,K]*B[N,K]^T + bias ----------------
template<int OUTF32>
__global__ __launch_bounds__(256) void k_gemm(
    const u16* __restrict__ A, const u16* __restrict__ B,
    const float* __restrict__ bias, void* __restrict__ C,
    int lda, int ldb, int ldc, int K, int ncols)
{
  __shared__ char smem[32768];
  const int tid = threadIdx.x;
  const int l = tid & 63;
  const int w = tid >> 6;
  const int wr = w >> 1, wc = w & 1;
  const long tM = (long)blockIdx.x * 128;
  const long tN = (long)blockIdx.y * 128;

  f32x4 acc[4][4];
#pragma unroll
  for (int m = 0; m < 4; m++)
#pragma unroll
    for (int n = 0; n < 4; n++) acc[m][n] = {0.f, 0.f, 0.f, 0.f};

  const int nk = K >> 6;
  for (int kt = 0; kt < nk; ++kt) {
    const int k0 = kt << 6;
#pragma unroll
    for (int i = 0; i < 4; i++) {
      int cchunk = w * 4 + i;
      int c = cchunk * 64 + l;
      int row = c >> 3, k8 = c & 7;
      gload_lds16(A + (tM + row) * lda + k0 + k8 * 8, smem + cchunk * 1024);
      gload_lds16(B + (tN + row) * ldb + k0 + k8 * 8, smem + 16384 + cchunk * 1024);
    }
    __syncthreads();
#pragma unroll
    for (int kk = 0; kk < 2; kk++) {
      const int kb = kk * 64 + ((l >> 4) * 16);
      bf16x8 af[4], bfr[4];
#pragma unroll
      for (int m = 0; m < 4; m++) {
        int ra = wr * 64 + m * 16 + (l & 15);
        af[m] = *(const bf16x8*)(smem + ra * 128 + kb);
      }
#pragma unroll
      for (int n = 0; n < 4; n++) {
        int rb2 = wc * 64 + n * 16 + (l & 15);
        bfr[n] = *(const bf16x8*)(smem + 16384 + rb2 * 128 + kb);
      }
#pragma unroll
      for (int m = 0; m < 4; m++)
#pragma unroll
        for (int n = 0; n < 4; n++)
          acc[m][n] = __builtin_amdgcn_mfma_f32_16x16x32_bf16(af[m], bfr[n], acc[m][n], 0, 0, 0);
    }
    __syncthreads();
  }
#pragma unroll
  for (int n = 0; n < 4; n++) {
    long col = tN + wc * 64 + n * 16 + (l & 15);
    float bv = (col < ncols) ? bias[col] : 0.f;
    if (col < ncols) {
#pragma unroll
      for (int m = 0; m < 4; m++) {
        long row = tM + wr * 64 + m * 16 + ((l >> 4) * 4);
#pragma unroll
        for (int r = 0; r < 4; r++) {
          float v = acc[m][n][r] + bv;
          if (OUTF32) ((float*)C)[(row + r) * ldc + col] = v;
          else        ((u16*)C)[(row + r) * ldc + col] = f2bf(v);
        }
      }
    }
  }
}

// ---------------- i8 decoder GEMM: C[8064,VV] = catq @ decWq^T scaled + bias ---
// BK=128 per tile (16KB/matrix in LDS), 8 K-tiles, mfma_i32_16x16x64_i8.
// A/B fragments use identical (row,k-slot) addressing -> dot product is
// invariant to the hardware's internal k-slot permutation.
__global__ __launch_bounds__(256) void k_gemm_i8(
    const signed char* __restrict__ A,   // [8064][1024]
    const signed char* __restrict__ B,   // [NPAD][1024]
    const float* __restrict__ wscale,    // [NPAD] = rowmax/(127*127)
    const float* __restrict__ bias,      // [VV]
    float* __restrict__ C)               // [8064][VV]
{
  __shared__ char smem[32768];           // A 16KB linear [128][128] i8 + B 16KB
  const int tid = threadIdx.x;
  const int l = tid & 63;
  const int w = tid >> 6;
  const int wr = w >> 1, wc = w & 1;
  const long tM = (long)blockIdx.x * 128;
  const long tN = (long)blockIdx.y * 128;

  i32x4 acc[4][4];
#pragma unroll
  for (int m = 0; m < 4; m++)
#pragma unroll
    for (int n = 0; n < 4; n++) acc[m][n] = {0, 0, 0, 0};

  for (int kt = 0; kt < 8; ++kt) {
    const int k0 = kt << 7;
    // stage A+B tiles: 16 chunks of (64 lanes x 16B) each; 4 per wave
#pragma unroll
    for (int i = 0; i < 4; i++) {
      int j = w * 4 + i;                 // chunk 0..15
      int row = j * 8 + (l >> 3);        // [0,128)
      int k16 = l & 7;                   // 16B unit within 128-col row
      gload_lds16(A + (tM + row) * 1024 + k0 + k16 * 16, smem + j * 1024);
      gload_lds16(B + (tN + row) * 1024 + k0 + k16 * 16, smem + 16384 + j * 1024);
    }
    __syncthreads();
#pragma unroll
    for (int ks = 0; ks < 2; ks++) {
      const int kb = ks * 64 + ((l >> 4) * 16);
      i32x4 af[4], bfr[4];
#pragma unroll
      for (int m = 0; m < 4; m++) {
        int ra = wr * 64 + m * 16 + (l & 15);
        af[m] = *(const i32x4*)(smem + ra * 128 + kb);
      }
#pragma unroll
      for (int n = 0; n < 4; n++) {
        int rb2 = wc * 64 + n * 16 + (l & 15);
        bfr[n] = *(const i32x4*)(smem + 16384 + rb2 * 128 + kb);
      }
#pragma unroll
      for (int m = 0; m < 4; m++)
#pragma unroll
        for (int n = 0; n < 4; n++)
          acc[m][n] = __builtin_amdgcn_mfma_i32_16x16x64_i8(af[m], bfr[n], acc[m][n], 0, 0, 0);
    }
    __syncthreads();
  }
  // epilogue: dequant + bias
#pragma unroll
  for (int n = 0; n < 4; n++) {
    long col = tN + wc * 64 + n * 16 + (l & 15);
    if (col < VV) {
      float sc = wscale[col];
      float bv = bias[col];
#pragma unroll
      for (int m = 0; m < 4; m++) {
        long row = tM + wr * 64 + m * 16 + ((l >> 4) * 4);
#pragma unroll
        for (int r = 0; r < 4; r++)
          C[(row + r) * VV + col] = (float)acc[m][n][r] * sc + bv;
      }
    }
  }
}

// ---------------- GRU recurrence (Round-11 proven structure) ----------------
__global__ __launch_bounds__(256) void k_gru(
    const u16* __restrict__ Whh_all,   // [2][1536][512] bf16
    const float* __restrict__ bhh_f, const float* __restrict__ bhh_b,
    const u16* __restrict__ gx_all,    // [2][8192][1536] bf16
    u16* __restrict__ hsteps,          // [129][2][64][512] bf16
    u16* __restrict__ cat,             // [8064][1024] bf16
    int* __restrict__ bar16)           // [2][128][16][FP]
{
  const int blk = blockIdx.x;
  const int dir = blockIdx.y;
  const int tid = threadIdx.x;
  const int l = tid & 63, w = tid >> 6;
  const u16* Whh = Whh_all + (long)dir * G3 * HH;
  const float* bhh = dir ? bhh_b : bhh_f;
  const u16* gx = gx_all + (long)dir * MROWS * G3;

  __shared__ char Wl[96 * 1024];               // 96 rows x 512 bf16, swizzled
  __shared__ __align__(16) u16 hstage[BB][32]; // 4KB repack tile

  for (int c = tid; c < 6144; c += 256) {
    int lr = c >> 6;
    int k8 = c & 63;
    int gr = (lr >> 5) * HH + blk * 32 + (lr & 31);
    uint4 v = *(const uint4*)(Whh + (long)gr * HH + k8 * 8);
    *(uint4*)(Wl + lr * 1024 + ((k8 * 16) ^ ((lr & 7) << 4))) = v;
  }
  float bh[6];
#pragma unroll
  for (int n = 0; n < 6; n++) {
    int c = n * 16 + (l & 15);
    bh[n] = bhh[(c >> 5) * HH + blk * 32 + (c & 31)];
  }
  float hreg[4][2] = {};
  __syncthreads();

  const int lrow = w * 16 + ((l >> 4) * 4);
  const int srow = tid >> 2, schunk = tid & 3;

  for (int t = 0; t < LL; ++t) {
    const int lpos = dir ? (LL - 1 - t) : t;
    const u16* hsrc = hsteps + ((size_t)t * 2 + dir) * BB * HH;

    bf16x8 af[16];
    {
      const u16* hrow = hsrc + (w * 16 + (l & 15)) * HH + ((l >> 4) * 8);
#pragma unroll
      for (int kc = 0; kc < 16; kc++) af[kc] = *(const bf16x8*)(hrow + kc * 32);
    }
    u16 gxv[3][4][2];
#pragma unroll
    for (int r = 0; r < 4; r++) {
      const u16* gxr = gx + ((long)lpos * BB + (lrow + r)) * G3 + blk * 32;
#pragma unroll
      for (int g = 0; g < 3; g++)
#pragma unroll
        for (int p = 0; p < 2; p++)
          gxv[g][r][p] = gxr[g * HH + p * 16 + (l & 15)];
    }

    f32x4 acc[6];
#pragma unroll
    for (int n = 0; n < 6; n++) acc[n] = {0.f, 0.f, 0.f, 0.f};
#pragma unroll
    for (int kc = 0; kc < 16; kc++) {
      const int kb = kc * 64 + ((l >> 4) * 16);
#pragma unroll
      for (int n = 0; n < 6; n++) {
        int lr = n * 16 + (l & 15);
        bf16x8 bfr = *(const bf16x8*)(Wl + lr * 1024 + (kb ^ ((l & 7) << 4)));
        acc[n] = __builtin_amdgcn_mfma_f32_16x16x32_bf16(af[kc], bfr, acc[n], 0, 0, 0);
      }
    }

#pragma unroll
    for (int r = 0; r < 4; r++) {
#pragma unroll
      for (int p = 0; p < 2; p++) {
        float ghr = acc[0 + p][r] + bh[0 + p];
        float ghz = acc[2 + p][r] + bh[2 + p];
        float ghn = acc[4 + p][r] + bh[4 + p];
        float xr = bf2f(gxv[0][r][p]);
        float xz = bf2f(gxv[1][r][p]);
        float xn = bf2f(gxv[2][r][p]);
        float ar = fminf(fmaxf(xr + ghr, -30.f), 30.f);
        float az = fminf(fmaxf(xz + ghz, -30.f), 30.f);
        float rg = 1.f / (1.f + __expf(-ar));
        float zg = 1.f / (1.f + __expf(-az));
        float an = fminf(fmaxf(xn + rg * ghn, -30.f), 30.f);
        float e2 = __expf(-2.f * an);
        float ng = (1.f - e2) / (1.f + e2);
        float hn = (1.f - zg) * ng + zg * hreg[r][p];
        hreg[r][p] = hn;
        hstage[lrow + r][p * 16 + (l & 15)] = f2bf(hn);
      }
    }
    __syncthreads();

    u32x4 hv = *(const u32x4*)&hstage[srow][schunk * 8];
    if (t < LL - 1) {
      u16* hdst = hsteps + ((size_t)(t + 1) * 2 + dir) * BB * HH;
      cstore16(hdst + srow * HH + blk * 32 + schunk * 8, hv);
      asm volatile("s_waitcnt vmcnt(0)" ::: "memory");
      __syncthreads();
      if (tid == 0)
        flagstore4(&bar16[((dir * LL + t) * 16 + blk) * FP], 1);
      const int* flg = bar16 + (dir * LL + t) * 16 * FP;
      for (;;) {
        int v = 1;
        if (l < 16) v = flagload4(&flg[l * FP]);
        if (__all(v != 0)) break;
      }
      __builtin_amdgcn_sched_barrier(0);
    }
    if (dir == 0) {
      if (lpos < LL - 2)
        *(u32x4*)(cat + ((long)lpos * BB + srow) * D2H + blk * 32 + schunk * 8) = hv;
    } else {
      if (lpos >= 2)
        *(u32x4*)(cat + ((long)(lpos - 2) * BB + srow) * D2H + HH + blk * 32 + schunk * 8) = hv;
    }
  }
}

// ---------------- log-softmax over V=10000 per row ----------------
__global__ __launch_bounds__(256) void k_lsm(float* __restrict__ out) {
  const long row = blockIdx.x;
  float* p = out + row * VV;
  const int tid = threadIdx.x;
  const int l = tid & 63, w = tid >> 6;
  __shared__ float red[8];

  float4 v[10];
  float m = -1e30f;
#pragma unroll
  for (int j = 0; j < 10; j++) {
    int idx = j * 256 + tid;
    if (idx < 2500) {
      v[j] = *(float4*)(p + idx * 4);
      m = fmaxf(m, fmaxf(fmaxf(v[j].x, v[j].y), fmaxf(v[j].z, v[j].w)));
    }
  }
#pragma unroll
  for (int off = 32; off; off >>= 1) m = fmaxf(m, __shfl_xor(m, off));
  if (l == 0) red[w] = m;
  __syncthreads();
  m = fmaxf(fmaxf(red[0], red[1]), fmaxf(red[2], red[3]));

  float s = 0.f;
#pragma unroll
  for (int j = 0; j < 10; j++) {
    int idx = j * 256 + tid;
    if (idx < 2500) {
      s += __expf(v[j].x - m) + __expf(v[j].y - m) + __expf(v[j].z - m) + __expf(v[j].w - m);
    }
  }
#pragma unroll
  for (int off = 32; off; off >>= 1) s += __shfl_xor(s, off);
  if (l == 0) red[4 + w] = s;
  __syncthreads();
  s = red[4] + red[5] + red[6] + red[7];
  float lse = m + logf(s);

#pragma unroll
  for (int j = 0; j < 10; j++) {
    int idx = j * 256 + tid;
    if (idx < 2500) {
      float4 o;
      o.x = v[j].x - lse; o.y = v[j].y - lse; o.z = v[j].z - lse; o.w = v[j].w - lse;
      *(float4*)(p + idx * 4) = o;
    }
  }
}

// ---------------- launch ----------------
extern "C" void kernel_launch(void* const* d_in, const int* in_sizes, int n_in,
                              void* d_out, int out_size, void* d_ws, size_t ws_size,
                              hipStream_t stream) {
  const int*   seq  = (const int*)d_in[0];
  const float* emb  = (const float*)d_in[2];
  const float* Wihf = (const float*)d_in[3];
  const float* Whhf = (const float*)d_in[4];
  const float* bihf = (const float*)d_in[5];
  const float* bhhf = (const float*)d_in[6];
  const float* Wihb = (const float*)d_in[7];
  const float* Whhb = (const float*)d_in[8];
  const float* bihb = (const float*)d_in[9];
  const float* bhhb = (const float*)d_in[10];
  const float* decW = (const float*)d_in[11];
  const float* decb = (const float*)d_in[12];

  char* ws = (char*)d_ws;
  size_t off = 0;
  u16* Whh_bf = (u16*)(ws + off); off += (size_t)2 * G3 * HH * 2;        // 3.1M
  u16* Wih_bf = (u16*)(ws + off); off += (size_t)2 * G3 * EE * 2;        // 3.1M
  signed char* decWq = (signed char*)(ws + off); off += (size_t)NPAD * 1024; // 10.4M
  float* wscale = (float*)(ws + off); off += (size_t)NPAD * 4;           // 40K
  u16* xb = (u16*)(ws + off); off += (size_t)MROWS * EE * 2;             // 8.4M
  u16* gxb = (u16*)(ws + off); off += (size_t)2 * MROWS * G3 * 2;        // 50.3M
  u16* cat = (u16*)(ws + off); off += (size_t)DM * D2H * 2;              // 16.5M
  signed char* catq = (signed char*)(ws + off); off += (size_t)DM * D2H; // 8.25M
  u16* hsteps = (u16*)(ws + off); off += (size_t)(LL + 1) * 2 * BB * HH * 2; // 16.9M
  int* bar16 = (int*)(ws + off); off += (size_t)2 * LL * 16 * FP * 4;    // 2M

  // zero hstep[0] (both dirs) + flags — every call so replays reset
  (void)hipMemsetAsync(hsteps, 0, (size_t)2 * BB * HH * 2, stream);
  (void)hipMemsetAsync(bar16, 0, (size_t)2 * LL * 16 * FP * 4, stream);

  const int n4w = G3 * HH / 4;
  k_cast<<<(n4w + 255) / 256, 256, 0, stream>>>((const float4*)Whhf, (ushort4*)(Whh_bf), n4w);
  k_cast<<<(n4w + 255) / 256, 256, 0, stream>>>((const float4*)Whhb, (ushort4*)(Whh_bf + G3 * HH), n4w);
  k_cast<<<(n4w + 255) / 256, 256, 0, stream>>>((const float4*)Wihf, (ushort4*)(Wih_bf), n4w);
  k_cast<<<(n4w + 255) / 256, 256, 0, stream>>>((const float4*)Wihb, (ushort4*)(Wih_bf + G3 * EE), n4w);
  k_quant_w<<<VV, 256, 0, stream>>>(decW, decWq, wscale);
  k_embed<<<MROWS, 128, 0, stream>>>(seq, emb, xb);

  k_gemm<0><<<dim3(64, 12), 256, 0, stream>>>(xb, Wih_bf, bihf, gxb, EE, EE, G3, EE, G3);
  k_gemm<0><<<dim3(64, 12), 256, 0, stream>>>(xb, Wih_bf + G3 * EE, bihb, gxb + (size_t)MROWS * G3, EE, EE, G3, EE, G3);

  k_gru<<<dim3(16, 2), 256, 0, stream>>>(Whh_bf, bhhf, bhhb, gxb, hsteps, cat, bar16);

  k_quant_a<<<(DM * D2H / 4 + 255) / 256, 256, 0, stream>>>(cat, catq, DM * D2H / 4);
  k_gemm_i8<<<dim3(63, 79), 256, 0, stream>>>(catq, decWq, wscale, decb, (float*)d_out);

  k_lsm<<<DM, 256, 0, stream>>>((float*)d_out);
}

// Round 13
// 1183.228 us; speedup vs baseline: 1.3184x; 1.0245x over previous
//
#include <hip/hip_runtime.h>
#include <hip/hip_bf16.h>
#include <stdint.h>

#define LL 128
#define BB 64
#define VV 10000
#define EE 512
#define HH 512
#define G3 1536
#define MROWS 8192      // L*B
#define DM 8064         // (L-2)*B
#define D2H 1024
#define NPAD 10112      // 79*128
#define FP 16           // flag padding (ints) -> one 64B line per producer

typedef __bf16 bf16x8 __attribute__((ext_vector_type(8)));
typedef float f32x4 __attribute__((ext_vector_type(4)));
typedef int i32x4 __attribute__((ext_vector_type(4)));
typedef unsigned int u32x4 __attribute__((ext_vector_type(4)));
typedef unsigned short u16;
typedef unsigned long long u64;

static __device__ __forceinline__ float bf2f(u16 u) {
  unsigned int x = ((unsigned int)u) << 16;
  return __builtin_bit_cast(float, x);
}
static __device__ __forceinline__ u16 f2bf(float f) {
  unsigned int x = __builtin_bit_cast(unsigned int, f);
  unsigned int r = x + 0x7FFFu + ((x >> 16) & 1u);
  return (u16)(r >> 16);
}
static __device__ __forceinline__ signed char q8(float v) {
  float r = fminf(fmaxf(rintf(v), -127.f), 127.f);
  return (signed char)(int)r;
}

// device-coherent (L1+L2-bypassing, visible at L3) ops — producers/flags only
static __device__ __forceinline__ void cstore16(void* p, u32x4 v) {
  asm volatile("global_store_dwordx4 %0, %1, off sc0 sc1" :: "v"(p), "v"(v) : "memory");
}
static __device__ __forceinline__ void flagstore4(void* p, int v) {
  asm volatile("global_store_dword %0, %1, off sc0 sc1" :: "v"(p), "v"(v) : "memory");
}
static __device__ __forceinline__ int flagload4(const void* p) {
  int v;
  asm volatile("global_load_dword %0, %1, off sc0 sc1\n\ts_waitcnt vmcnt(0)"
               : "=v"(v) : "v"(p) : "memory");
  return v;
}
// async global->LDS, 16B per lane: LDS dest = wave-uniform base + lane*16
static __device__ __forceinline__ void gload_lds16(const void* g, void* s) {
  __builtin_amdgcn_global_load_lds(
      (const __attribute__((address_space(1))) unsigned int*)g,
      (__attribute__((address_space(3))) unsigned int*)s, 16, 0, 0);
}

// ---------------- cast / quant kernels ----------------
__global__ void k_cast(const float4* __restrict__ src, ushort4* __restrict__ dst, int n4) {
  int i = blockIdx.x * blockDim.x + threadIdx.x;
  if (i < n4) {
    float4 v = src[i];
    ushort4 o;
    o.x = f2bf(v.x); o.y = f2bf(v.y); o.z = f2bf(v.z); o.w = f2bf(v.w);
    dst[i] = o;
  }
}

// decW [VV][1024] f32 -> per-row-scaled i8 + wscale[v] = rowmax/(127*127)
__global__ __launch_bounds__(256) void k_quant_w(const float* __restrict__ W,
                                                 signed char* __restrict__ Q,
                                                 float* __restrict__ wscale) {
  const int v = blockIdx.x;
  const int tid = threadIdx.x;
  const int l = tid & 63, w = tid >> 6;
  float4 x = *(const float4*)(W + (long)v * 1024 + tid * 4);
  float m = fmaxf(fmaxf(fabsf(x.x), fabsf(x.y)), fmaxf(fabsf(x.z), fabsf(x.w)));
#pragma unroll
  for (int off = 32; off; off >>= 1) m = fmaxf(m, __shfl_xor(m, off));
  __shared__ float red[4];
  __shared__ float s_inv;
  if (l == 0) red[w] = m;
  __syncthreads();
  if (tid == 0) {
    float mm = fmaxf(fmaxf(red[0], red[1]), fmaxf(red[2], red[3]));
    mm = fmaxf(mm, 1e-12f);
    s_inv = 127.f / mm;
    wscale[v] = mm / (127.f * 127.f);
  }
  __syncthreads();
  float inv = s_inv;
  char4 o;
  o.x = q8(x.x * inv); o.y = q8(x.y * inv); o.z = q8(x.z * inv); o.w = q8(x.w * inv);
  *(char4*)(Q + (long)v * 1024 + tid * 4) = o;
}

__global__ void k_embed(const int* __restrict__ seq, const float* __restrict__ emb,
                        u16* __restrict__ x) {
  int rb = blockIdx.x;
  int v = seq[rb];
  const float4* s = (const float4*)(emb + (long)v * EE);
  ushort4* d = (ushort4*)(x + (long)rb * EE);
  int t = threadIdx.x;
  float4 val = s[t];
  ushort4 o;
  o.x = f2bf(val.x); o.y = f2bf(val.y); o.z = f2bf(val.z); o.w = f2bf(val.w);
  d[t] = o;
}

// ---------------- bf16 GEMM (gx): C[M,N] = A[M,K]*B[N,K]^T + bias ----------------
template<int OUTF32>
__global__ __launch_bounds__(256) void k_gemm(
    const u16* __restrict__ A, const u16* __restrict__ B,
    const float* __restrict__ bias, void* __restrict__ C,
    int lda, int ldb, int ldc, int K, int ncols)
{
  __shared__ char smem[32768];
  const int tid = threadIdx.x;
  const int l = tid & 63;
  const int w = tid >> 6;
  const int wr = w >> 1, wc = w & 1;
  const long tM = (long)blockIdx.x * 128;
  const long tN = (long)blockIdx.y * 128;

  f32x4 acc[4][4];
#pragma unroll
  for (int m = 0; m < 4; m++)
#pragma unroll
    for (int n = 0; n < 4; n++) acc[m][n] = {0.f, 0.f, 0.f, 0.f};

  const int nk = K >> 6;
  for (int kt = 0; kt < nk; ++kt) {
    const int k0 = kt << 6;
#pragma unroll
    for (int i = 0; i < 4; i++) {
      int cchunk = w * 4 + i;
      int c = cchunk * 64 + l;
      int row = c >> 3, k8 = c & 7;
      gload_lds16(A + (tM + row) * lda + k0 + k8 * 8, smem + cchunk * 1024);
      gload_lds16(B + (tN + row) * ldb + k0 + k8 * 8, smem + 16384 + cchunk * 1024);
    }
    __syncthreads();
#pragma unroll
    for (int kk = 0; kk < 2; kk++) {
      const int kb = kk * 64 + ((l >> 4) * 16);
      bf16x8 af[4], bfr[4];
#pragma unroll
      for (int m = 0; m < 4; m++) {
        int ra = wr * 64 + m * 16 + (l & 15);
        af[m] = *(const bf16x8*)(smem + ra * 128 + kb);
      }
#pragma unroll
      for (int n = 0; n < 4; n++) {
        int rb2 = wc * 64 + n * 16 + (l & 15);
        bfr[n] = *(const bf16x8*)(smem + 16384 + rb2 * 128 + kb);
      }
#pragma unroll
      for (int m = 0; m < 4; m++)
#pragma unroll
        for (int n = 0; n < 4; n++)
          acc[m][n] = __builtin_amdgcn_mfma_f32_16x16x32_bf16(af[m], bfr[n], acc[m][n], 0, 0, 0);
    }
    __syncthreads();
  }
#pragma unroll
  for (int n = 0; n < 4; n++) {
    long col = tN + wc * 64 + n * 16 + (l & 15);
    float bv = (col < ncols) ? bias[col] : 0.f;
    if (col < ncols) {
#pragma unroll
      for (int m = 0; m < 4; m++) {
        long row = tM + wr * 64 + m * 16 + ((l >> 4) * 4);
#pragma unroll
        for (int r = 0; r < 4; r++) {
          float v = acc[m][n][r] + bv;
          if (OUTF32) ((float*)C)[(row + r) * ldc + col] = v;
          else        ((u16*)C)[(row + r) * ldc + col] = f2bf(v);
        }
      }
    }
  }
}

// ---------------- i8 decoder GEMM: C[8064,VV] = catq @ decWq^T scaled + bias ---
__global__ __launch_bounds__(256) void k_gemm_i8(
    const signed char* __restrict__ A,   // [8064][1024]
    const signed char* __restrict__ B,   // [NPAD][1024]
    const float* __restrict__ wscale,    // [NPAD]
    const float* __restrict__ bias,      // [VV]
    float* __restrict__ C)               // [8064][VV]
{
  __shared__ char smem[32768];
  const int tid = threadIdx.x;
  const int l = tid & 63;
  const int w = tid >> 6;
  const int wr = w >> 1, wc = w & 1;
  const long tM = (long)blockIdx.x * 128;
  const long tN = (long)blockIdx.y * 128;

  i32x4 acc[4][4];
#pragma unroll
  for (int m = 0; m < 4; m++)
#pragma unroll
    for (int n = 0; n < 4; n++) acc[m][n] = {0, 0, 0, 0};

  for (int kt = 0; kt < 8; ++kt) {
    const int k0 = kt << 7;
#pragma unroll
    for (int i = 0; i < 4; i++) {
      int j = w * 4 + i;
      int row = j * 8 + (l >> 3);
      int k16 = l & 7;
      gload_lds16(A + (tM + row) * 1024 + k0 + k16 * 16, smem + j * 1024);
      gload_lds16(B + (tN + row) * 1024 + k0 + k16 * 16, smem + 16384 + j * 1024);
    }
    __syncthreads();
#pragma unroll
    for (int ks = 0; ks < 2; ks++) {
      const int kb = ks * 64 + ((l >> 4) * 16);
      i32x4 af[4], bfr[4];
#pragma unroll
      for (int m = 0; m < 4; m++) {
        int ra = wr * 64 + m * 16 + (l & 15);
        af[m] = *(const i32x4*)(smem + ra * 128 + kb);
      }
#pragma unroll
      for (int n = 0; n < 4; n++) {
        int rb2 = wc * 64 + n * 16 + (l & 15);
        bfr[n] = *(const i32x4*)(smem + 16384 + rb2 * 128 + kb);
      }
#pragma unroll
      for (int m = 0; m < 4; m++)
#pragma unroll
        for (int n = 0; n < 4; n++)
          acc[m][n] = __builtin_amdgcn_mfma_i32_16x16x64_i8(af[m], bfr[n], acc[m][n], 0, 0, 0);
    }
    __syncthreads();
  }
#pragma unroll
  for (int n = 0; n < 4; n++) {
    long col = tN + wc * 64 + n * 16 + (l & 15);
    if (col < VV) {
      float sc = wscale[col];
      float bv = bias[col];
#pragma unroll
      for (int m = 0; m < 4; m++) {
        long row = tM + wr * 64 + m * 16 + ((l >> 4) * 4);
#pragma unroll
        for (int r = 0; r < 4; r++)
          C[(row + r) * VV + col] = (float)acc[m][n][r] * sc + bv;
      }
    }
  }
}

// ---------------- GRU recurrence ----------------
// Round-11 sync structure + (a) compiler-scheduled counted waits (no manual
// pre-MFMA drain), (b) gx(t+1) prefetched during the sync tail (drained by the
// poll's embedded vmcnt(0), overlapping the flag RT), (c) direct i8 cat store.
__global__ __launch_bounds__(256) void k_gru(
    const u16* __restrict__ Whh_all,   // [2][1536][512] bf16
    const float* __restrict__ bhh_f, const float* __restrict__ bhh_b,
    const u16* __restrict__ gx_all,    // [2][8192][1536] bf16
    u16* __restrict__ hsteps,          // [129][2][64][512] bf16
    signed char* __restrict__ catq,    // [8064][1024] i8 (scale 127)
    int* __restrict__ bar16)           // [2][128][16][FP]
{
  const int blk = blockIdx.x;
  const int dir = blockIdx.y;
  const int tid = threadIdx.x;
  const int l = tid & 63, w = tid >> 6;
  const u16* Whh = Whh_all + (long)dir * G3 * HH;
  const float* bhh = dir ? bhh_b : bhh_f;
  const u16* gx = gx_all + (long)dir * MROWS * G3;

  __shared__ char Wl[96 * 1024];               // 96 rows x 512 bf16, swizzled
  __shared__ __align__(16) u16 hstage[BB][32]; // 4KB bf16 repack tile
  __shared__ __align__(8) signed char hstageq[BB][32]; // 2KB i8 repack tile

  for (int c = tid; c < 6144; c += 256) {
    int lr = c >> 6;
    int k8 = c & 63;
    int gr = (lr >> 5) * HH + blk * 32 + (lr & 31);
    uint4 v = *(const uint4*)(Whh + (long)gr * HH + k8 * 8);
    *(uint4*)(Wl + lr * 1024 + ((k8 * 16) ^ ((lr & 7) << 4))) = v;
  }
  float bh[6];
#pragma unroll
  for (int n = 0; n < 6; n++) {
    int c = n * 16 + (l & 15);
    bh[n] = bhh[(c >> 5) * HH + blk * 32 + (c & 31)];
  }
  float hreg[4][2] = {};
  __syncthreads();

  const int lrow = w * 16 + ((l >> 4) * 4);
  const int srow = tid >> 2, schunk = tid & 3;

  // prologue gx prefetch (step 0)
  u16 gxn[3][4][2];
  {
    const int lpos0 = dir ? (LL - 1) : 0;
#pragma unroll
    for (int r = 0; r < 4; r++) {
      const u16* gxr = gx + ((long)lpos0 * BB + (lrow + r)) * G3 + blk * 32;
#pragma unroll
      for (int g = 0; g < 3; g++)
#pragma unroll
        for (int p = 0; p < 2; p++)
          gxn[g][r][p] = gxr[g * HH + p * 16 + (l & 15)];
    }
  }

  for (int t = 0; t < LL; ++t) {
    const int lpos = dir ? (LL - 1 - t) : t;
    const u16* hsrc = hsteps + ((size_t)t * 2 + dir) * BB * HH;

    // consume prefetched gx
    u16 gxv[3][4][2];
#pragma unroll
    for (int g = 0; g < 3; g++)
#pragma unroll
      for (int r = 0; r < 4; r++)
#pragma unroll
        for (int p = 0; p < 2; p++) gxv[g][r][p] = gxn[g][r][p];

    // h tile load: plain cached wide loads; compiler inserts the counted
    // waitcnt before first MFMA use (no manual full drain)
    bf16x8 af[16];
    {
      const u16* hrow = hsrc + (w * 16 + (l & 15)) * HH + ((l >> 4) * 8);
#pragma unroll
      for (int kc = 0; kc < 16; kc++) af[kc] = *(const bf16x8*)(hrow + kc * 32);
    }

    // MFMA: gh[64 x 96]
    f32x4 acc[6];
#pragma unroll
    for (int n = 0; n < 6; n++) acc[n] = {0.f, 0.f, 0.f, 0.f};
#pragma unroll
    for (int kc = 0; kc < 16; kc++) {
      const int kb = kc * 64 + ((l >> 4) * 16);
#pragma unroll
      for (int n = 0; n < 6; n++) {
        int lr = n * 16 + (l & 15);
        bf16x8 bfr = *(const bf16x8*)(Wl + lr * 1024 + (kb ^ ((l & 7) << 4)));
        acc[n] = __builtin_amdgcn_mfma_f32_16x16x32_bf16(af[kc], bfr, acc[n], 0, 0, 0);
      }
    }

    // gates -> bf16 stage + i8 stage
#pragma unroll
    for (int r = 0; r < 4; r++) {
#pragma unroll
      for (int p = 0; p < 2; p++) {
        float ghr = acc[0 + p][r] + bh[0 + p];
        float ghz = acc[2 + p][r] + bh[2 + p];
        float ghn = acc[4 + p][r] + bh[4 + p];
        float xr = bf2f(gxv[0][r][p]);
        float xz = bf2f(gxv[1][r][p]);
        float xn = bf2f(gxv[2][r][p]);
        float ar = fminf(fmaxf(xr + ghr, -30.f), 30.f);
        float az = fminf(fmaxf(xz + ghz, -30.f), 30.f);
        float rg = 1.f / (1.f + __expf(-ar));
        float zg = 1.f / (1.f + __expf(-az));
        float an = fminf(fmaxf(xn + rg * ghn, -30.f), 30.f);
        float e2 = __expf(-2.f * an);
        float ng = (1.f - e2) / (1.f + e2);
        float hn = (1.f - zg) * ng + zg * hreg[r][p];
        hreg[r][p] = hn;
        hstage[lrow + r][p * 16 + (l & 15)] = f2bf(hn);
        hstageq[lrow + r][p * 16 + (l & 15)] = q8(hn * 127.f);
      }
    }
    __syncthreads();

    u32x4 hv = *(const u32x4*)&hstage[srow][schunk * 8];
    u64 hq = *(const u64*)&hstageq[srow][schunk * 8];
    if (t < LL - 1) {
      u16* hdst = hsteps + ((size_t)(t + 1) * 2 + dir) * BB * HH;
      cstore16(hdst + srow * HH + blk * 32 + schunk * 8, hv);
      asm volatile("s_waitcnt vmcnt(0)" ::: "memory");
      __syncthreads();
      if (tid == 0)
        flagstore4(&bar16[((dir * LL + t) * 16 + blk) * FP], 1);
      // prefetch gx for step t+1 — completes under the poll's vmcnt(0)
      {
        const int lposn = dir ? (LL - 2 - t) : (t + 1);
#pragma unroll
        for (int r = 0; r < 4; r++) {
          const u16* gxr = gx + ((long)lposn * BB + (lrow + r)) * G3 + blk * 32;
#pragma unroll
          for (int g = 0; g < 3; g++)
#pragma unroll
            for (int p = 0; p < 2; p++)
              gxn[g][r][p] = gxr[g * HH + p * 16 + (l & 15)];
        }
      }
      // catq store (plain; consumed next kernel)
      if (dir == 0) {
        if (lpos < LL - 2)
          *(u64*)(catq + ((long)lpos * BB + srow) * D2H + blk * 32 + schunk * 8) = hq;
      } else {
        if (lpos >= 2)
          *(u64*)(catq + ((long)(lpos - 2) * BB + srow) * D2H + HH + blk * 32 + schunk * 8) = hq;
      }
      // poll all 16 producer flags
      const int* flg = bar16 + (dir * LL + t) * 16 * FP;
      for (;;) {
        int v = 1;
        if (l < 16) v = flagload4(&flg[l * FP]);
        if (__all(v != 0)) break;
      }
      __builtin_amdgcn_sched_barrier(0);
    } else {
      if (dir == 0) {
        if (lpos < LL - 2)
          *(u64*)(catq + ((long)lpos * BB + srow) * D2H + blk * 32 + schunk * 8) = hq;
      } else {
        if (lpos >= 2)
          *(u64*)(catq + ((long)(lpos - 2) * BB + srow) * D2H + HH + blk * 32 + schunk * 8) = hq;
      }
    }
  }
}

// ---------------- log-softmax over V=10000 per row ----------------
__global__ __launch_bounds__(256) void k_lsm(float* __restrict__ out) {
  const long row = blockIdx.x;
  float* p = out + row * VV;
  const int tid = threadIdx.x;
  const int l = tid & 63, w = tid >> 6;
  __shared__ float red[8];

  float4 v[10];
  float m = -1e30f;
#pragma unroll
  for (int j = 0; j < 10; j++) {
    int idx = j * 256 + tid;
    if (idx < 2500) {
      v[j] = *(float4*)(p + idx * 4);
      m = fmaxf(m, fmaxf(fmaxf(v[j].x, v[j].y), fmaxf(v[j].z, v[j].w)));
    }
  }
#pragma unroll
  for (int off = 32; off; off >>= 1) m = fmaxf(m, __shfl_xor(m, off));
  if (l == 0) red[w] = m;
  __syncthreads();
  m = fmaxf(fmaxf(red[0], red[1]), fmaxf(red[2], red[3]));

  float s = 0.f;
#pragma unroll
  for (int j = 0; j < 10; j++) {
    int idx = j * 256 + tid;
    if (idx < 2500) {
      s += __expf(v[j].x - m) + __expf(v[j].y - m) + __expf(v[j].z - m) + __expf(v[j].w - m);
    }
  }
#pragma unroll
  for (int off = 32; off; off >>= 1) s += __shfl_xor(s, off);
  if (l == 0) red[4 + w] = s;
  __syncthreads();
  s = red[4] + red[5] + red[6] + red[7];
  float lse = m + logf(s);

#pragma unroll
  for (int j = 0; j < 10; j++) {
    int idx = j * 256 + tid;
    if (idx < 2500) {
      float4 o;
      o.x = v[j].x - lse; o.y = v[j].y - lse; o.z = v[j].z - lse; o.w = v[j].w - lse;
      *(float4*)(p + idx * 4) = o;
    }
  }
}

// ---------------- launch ----------------
extern "C" void kernel_launch(void* const* d_in, const int* in_sizes, int n_in,
                              void* d_out, int out_size, void* d_ws, size_t ws_size,
                              hipStream_t stream) {
  const int*   seq  = (const int*)d_in[0];
  const float* emb  = (const float*)d_in[2];
  const float* Wihf = (const float*)d_in[3];
  const float* Whhf = (const float*)d_in[4];
  const float* bihf = (const float*)d_in[5];
  const float* bhhf = (const float*)d_in[6];
  const float* Wihb = (const float*)d_in[7];
  const float* Whhb = (const float*)d_in[8];
  const float* bihb = (const float*)d_in[9];
  const float* bhhb = (const float*)d_in[10];
  const float* decW = (const float*)d_in[11];
  const float* decb = (const float*)d_in[12];

  char* ws = (char*)d_ws;
  size_t off = 0;
  u16* Whh_bf = (u16*)(ws + off); off += (size_t)2 * G3 * HH * 2;        // 3.1M
  u16* Wih_bf = (u16*)(ws + off); off += (size_t)2 * G3 * EE * 2;        // 3.1M
  signed char* decWq = (signed char*)(ws + off); off += (size_t)NPAD * 1024; // 10.4M
  float* wscale = (float*)(ws + off); off += (size_t)NPAD * 4;           // 40K
  u16* xb = (u16*)(ws + off); off += (size_t)MROWS * EE * 2;             // 8.4M
  u16* gxb = (u16*)(ws + off); off += (size_t)2 * MROWS * G3 * 2;        // 50.3M
  signed char* catq = (signed char*)(ws + off); off += (size_t)DM * D2H; // 8.25M
  u16* hsteps = (u16*)(ws + off); off += (size_t)(LL + 1) * 2 * BB * HH * 2; // 16.9M
  int* bar16 = (int*)(ws + off); off += (size_t)2 * LL * 16 * FP * 4;    // 2M

  // zero hstep[0] (both dirs) + flags — every call so replays reset
  (void)hipMemsetAsync(hsteps, 0, (size_t)2 * BB * HH * 2, stream);
  (void)hipMemsetAsync(bar16, 0, (size_t)2 * LL * 16 * FP * 4, stream);

  const int n4w = G3 * HH / 4;
  k_cast<<<(n4w + 255) / 256, 256, 0, stream>>>((const float4*)Whhf, (ushort4*)(Whh_bf), n4w);
  k_cast<<<(n4w + 255) / 256, 256, 0, stream>>>((const float4*)Whhb, (ushort4*)(Whh_bf + G3 * HH), n4w);
  k_cast<<<(n4w + 255) / 256, 256, 0, stream>>>((const float4*)Wihf, (ushort4*)(Wih_bf), n4w);
  k_cast<<<(n4w + 255) / 256, 256, 0, stream>>>((const float4*)Wihb, (ushort4*)(Wih_bf + G3 * EE), n4w);
  k_quant_w<<<VV, 256, 0, stream>>>(decW, decWq, wscale);
  k_embed<<<MROWS, 128, 0, stream>>>(seq, emb, xb);

  k_gemm<0><<<dim3(64, 12), 256, 0, stream>>>(xb, Wih_bf, bihf, gxb, EE, EE, G3, EE, G3);
  k_gemm<0><<<dim3(64, 12), 256, 0, stream>>>(xb, Wih_bf + G3 * EE, bihb, gxb + (size_t)MROWS * G3, EE, EE, G3, EE, G3);

  k_gru<<<dim3(16, 2), 256, 0, stream>>>(Whh_bf, bhhf, bhhb, gxb, hsteps, catq, bar16);

  k_gemm_i8<<<dim3(63, 79), 256, 0, stream>>>(catq, decWq, wscale, decb, (float*)d_out);

  k_lsm<<<DM, 256, 0, stream>>>((float*)d_out);
}

// Round 14
// 1098.489 us; speedup vs baseline: 1.4201x; 1.0771x over previous
//
#include <hip/hip_runtime.h>
#include <hip/hip_bf16.h>
#include <stdint.h>

#define LL 128
#define BB 64
#define VV 10000
#define EE 512
#define HH 512
#define G3 1536
#define MROWS 8192      // L*B
#define DM 8064         // (L-2)*B
#define D2H 1024
#define NPAD 10112      // 79*128
#define FP 16           // flag padding (ints) -> one 64B line per producer

typedef __bf16 bf16x8 __attribute__((ext_vector_type(8)));
typedef float f32x4 __attribute__((ext_vector_type(4)));
typedef int i32x4 __attribute__((ext_vector_type(4)));
typedef unsigned int u32x4 __attribute__((ext_vector_type(4)));
typedef unsigned short u16;
typedef unsigned long long u64;

static __device__ __forceinline__ float bf2f(u16 u) {
  unsigned int x = ((unsigned int)u) << 16;
  return __builtin_bit_cast(float, x);
}
static __device__ __forceinline__ u16 f2bf(float f) {
  unsigned int x = __builtin_bit_cast(unsigned int, f);
  unsigned int r = x + 0x7FFFu + ((x >> 16) & 1u);
  return (u16)(r >> 16);
}
static __device__ __forceinline__ signed char q8(float v) {
  float r = fminf(fmaxf(rintf(v), -127.f), 127.f);
  return (signed char)(int)r;
}

// device-coherent (L1+L2-bypassing, visible at L3) ops — producers/flags only
static __device__ __forceinline__ void cstore16(void* p, u32x4 v) {
  asm volatile("global_store_dwordx4 %0, %1, off sc0 sc1" :: "v"(p), "v"(v) : "memory");
}
static __device__ __forceinline__ void flagstore4(void* p, int v) {
  asm volatile("global_store_dword %0, %1, off sc0 sc1" :: "v"(p), "v"(v) : "memory");
}
static __device__ __forceinline__ int flagload4(const void* p) {
  int v;
  asm volatile("global_load_dword %0, %1, off sc0 sc1\n\ts_waitcnt vmcnt(0)"
               : "=v"(v) : "v"(p) : "memory");
  return v;
}
// async global->LDS, 16B per lane: LDS dest = wave-uniform base + lane*16
static __device__ __forceinline__ void gload_lds16(const void* g, void* s) {
  __builtin_amdgcn_global_load_lds(
      (const __attribute__((address_space(1))) unsigned int*)g,
      (__attribute__((address_space(3))) unsigned int*)s, 16, 0, 0);
}

// ---------------- cast / quant kernels ----------------
// 4 weight casts in one launch (blockIdx.y selects tensor)
__global__ void k_cast4(const float4* __restrict__ s0, const float4* __restrict__ s1,
                        const float4* __restrict__ s2, const float4* __restrict__ s3,
                        ushort4* __restrict__ d0, ushort4* __restrict__ d1,
                        ushort4* __restrict__ d2, ushort4* __restrict__ d3, int n4) {
  const float4* s; ushort4* d;
  switch (blockIdx.y) {
    case 0: s = s0; d = d0; break;
    case 1: s = s1; d = d1; break;
    case 2: s = s2; d = d2; break;
    default: s = s3; d = d3; break;
  }
  int i = blockIdx.x * blockDim.x + threadIdx.x;
  if (i < n4) {
    float4 v = s[i];
    ushort4 o;
    o.x = f2bf(v.x); o.y = f2bf(v.y); o.z = f2bf(v.z); o.w = f2bf(v.w);
    d[i] = o;
  }
}

// decW [VV][1024] f32 -> per-row-scaled i8 + wscale[v] = rowmax/(127*127)
__global__ __launch_bounds__(256) void k_quant_w(const float* __restrict__ W,
                                                 signed char* __restrict__ Q,
                                                 float* __restrict__ wscale) {
  const int v = blockIdx.x;
  const int tid = threadIdx.x;
  const int l = tid & 63, w = tid >> 6;
  float4 x = *(const float4*)(W + (long)v * 1024 + tid * 4);
  float m = fmaxf(fmaxf(fabsf(x.x), fabsf(x.y)), fmaxf(fabsf(x.z), fabsf(x.w)));
#pragma unroll
  for (int off = 32; off; off >>= 1) m = fmaxf(m, __shfl_xor(m, off));
  __shared__ float red[4];
  __shared__ float s_inv;
  if (l == 0) red[w] = m;
  __syncthreads();
  if (tid == 0) {
    float mm = fmaxf(fmaxf(red[0], red[1]), fmaxf(red[2], red[3]));
    mm = fmaxf(mm, 1e-12f);
    s_inv = 127.f / mm;
    wscale[v] = mm / (127.f * 127.f);
  }
  __syncthreads();
  float inv = s_inv;
  char4 o;
  o.x = q8(x.x * inv); o.y = q8(x.y * inv); o.z = q8(x.z * inv); o.w = q8(x.w * inv);
  *(char4*)(Q + (long)v * 1024 + tid * 4) = o;
}

__global__ void k_embed(const int* __restrict__ seq, const float* __restrict__ emb,
                        u16* __restrict__ x) {
  int rb = blockIdx.x;
  int v = seq[rb];
  const float4* s = (const float4*)(emb + (long)v * EE);
  ushort4* d = (ushort4*)(x + (long)rb * EE);
  int t = threadIdx.x;
  float4 val = s[t];
  ushort4 o;
  o.x = f2bf(val.x); o.y = f2bf(val.y); o.z = f2bf(val.z); o.w = f2bf(val.w);
  d[t] = o;
}

// ---------------- gx GEMM (both directions, blockIdx.z selects) -------------
// C[z][8192,1536] = xb[8192,512] @ Wih[z]^T + bih[z], bf16 out
__global__ __launch_bounds__(256) void k_gemm_gx(
    const u16* __restrict__ A, const u16* __restrict__ W0, const u16* __restrict__ W1,
    const float* __restrict__ b0, const float* __restrict__ b1, u16* __restrict__ C)
{
  __shared__ char smem[32768];
  const int tid = threadIdx.x;
  const int l = tid & 63;
  const int w = tid >> 6;
  const int wr = w >> 1, wc = w & 1;
  const long tM = (long)blockIdx.x * 128;
  const long tN = (long)blockIdx.y * 128;
  const int z = blockIdx.z;
  const u16* B = z ? W1 : W0;
  const float* bias = z ? b1 : b0;
  u16* Cz = C + (size_t)z * MROWS * G3;

  f32x4 acc[4][4];
#pragma unroll
  for (int m = 0; m < 4; m++)
#pragma unroll
    for (int n = 0; n < 4; n++) acc[m][n] = {0.f, 0.f, 0.f, 0.f};

  for (int kt = 0; kt < 8; ++kt) {
    const int k0 = kt << 6;
#pragma unroll
    for (int i = 0; i < 4; i++) {
      int cchunk = w * 4 + i;
      int c = cchunk * 64 + l;
      int row = c >> 3, k8 = c & 7;
      gload_lds16(A + (tM + row) * EE + k0 + k8 * 8, smem + cchunk * 1024);
      gload_lds16(B + (tN + row) * EE + k0 + k8 * 8, smem + 16384 + cchunk * 1024);
    }
    __syncthreads();
#pragma unroll
    for (int kk = 0; kk < 2; kk++) {
      const int kb = kk * 64 + ((l >> 4) * 16);
      bf16x8 af[4], bfr[4];
#pragma unroll
      for (int m = 0; m < 4; m++) {
        int ra = wr * 64 + m * 16 + (l & 15);
        af[m] = *(const bf16x8*)(smem + ra * 128 + kb);
      }
#pragma unroll
      for (int n = 0; n < 4; n++) {
        int rb2 = wc * 64 + n * 16 + (l & 15);
        bfr[n] = *(const bf16x8*)(smem + 16384 + rb2 * 128 + kb);
      }
#pragma unroll
      for (int m = 0; m < 4; m++)
#pragma unroll
        for (int n = 0; n < 4; n++)
          acc[m][n] = __builtin_amdgcn_mfma_f32_16x16x32_bf16(af[m], bfr[n], acc[m][n], 0, 0, 0);
    }
    __syncthreads();
  }
#pragma unroll
  for (int n = 0; n < 4; n++) {
    long col = tN + wc * 64 + n * 16 + (l & 15);
    float bv = bias[col];
#pragma unroll
    for (int m = 0; m < 4; m++) {
      long row = tM + wr * 64 + m * 16 + ((l >> 4) * 4);
#pragma unroll
      for (int r = 0; r < 4; r++)
        Cz[(row + r) * G3 + col] = f2bf(acc[m][n][r] + bv);
    }
  }
}

// ---------------- i8 decoder GEMM: logits = catq @ decWq^T scaled + bias -----
// OUTBF16=1: bf16 logits [DM][NPAD]; OUTBF16=0: f32 direct to d_out [DM][VV].
template<int OUTBF16>
__global__ __launch_bounds__(256) void k_gemm_i8(
    const signed char* __restrict__ A,   // [8064][1024]
    const signed char* __restrict__ B,   // [NPAD][1024]
    const float* __restrict__ wscale,    // [NPAD]
    const float* __restrict__ bias,      // [VV]
    void* __restrict__ Cv)
{
  __shared__ char smem[32768];
  const int tid = threadIdx.x;
  const int l = tid & 63;
  const int w = tid >> 6;
  const int wr = w >> 1, wc = w & 1;
  const long tM = (long)blockIdx.x * 128;
  const long tN = (long)blockIdx.y * 128;

  i32x4 acc[4][4];
#pragma unroll
  for (int m = 0; m < 4; m++)
#pragma unroll
    for (int n = 0; n < 4; n++) acc[m][n] = {0, 0, 0, 0};

  for (int kt = 0; kt < 8; ++kt) {
    const int k0 = kt << 7;
#pragma unroll
    for (int i = 0; i < 4; i++) {
      int j = w * 4 + i;
      int row = j * 8 + (l >> 3);
      int k16 = l & 7;
      gload_lds16(A + (tM + row) * 1024 + k0 + k16 * 16, smem + j * 1024);
      gload_lds16(B + (tN + row) * 1024 + k0 + k16 * 16, smem + 16384 + j * 1024);
    }
    __syncthreads();
#pragma unroll
    for (int ks = 0; ks < 2; ks++) {
      const int kb = ks * 64 + ((l >> 4) * 16);
      i32x4 af[4], bfr[4];
#pragma unroll
      for (int m = 0; m < 4; m++) {
        int ra = wr * 64 + m * 16 + (l & 15);
        af[m] = *(const i32x4*)(smem + ra * 128 + kb);
      }
#pragma unroll
      for (int n = 0; n < 4; n++) {
        int rb2 = wc * 64 + n * 16 + (l & 15);
        bfr[n] = *(const i32x4*)(smem + 16384 + rb2 * 128 + kb);
      }
#pragma unroll
      for (int m = 0; m < 4; m++)
#pragma unroll
        for (int n = 0; n < 4; n++)
          acc[m][n] = __builtin_amdgcn_mfma_i32_16x16x64_i8(af[m], bfr[n], acc[m][n], 0, 0, 0);
    }
    __syncthreads();
  }
#pragma unroll
  for (int n = 0; n < 4; n++) {
    long col = tN + wc * 64 + n * 16 + (l & 15);
    if (col < VV) {
      float sc = wscale[col];
      float bv = bias[col];
#pragma unroll
      for (int m = 0; m < 4; m++) {
        long row = tM + wr * 64 + m * 16 + ((l >> 4) * 4);
#pragma unroll
        for (int r = 0; r < 4; r++) {
          float vv = (float)acc[m][n][r] * sc + bv;
          if (OUTBF16) ((u16*)Cv)[(row + r) * NPAD + col] = f2bf(vv);
          else         ((float*)Cv)[(row + r) * VV + col] = vv;
        }
      }
    }
  }
}

// ---------------- GRU recurrence (Round-13 structure, unchanged) -------------
__global__ __launch_bounds__(256) void k_gru(
    const u16* __restrict__ Whh_all,   // [2][1536][512] bf16
    const float* __restrict__ bhh_f, const float* __restrict__ bhh_b,
    const u16* __restrict__ gx_all,    // [2][8192][1536] bf16
    u16* __restrict__ hsteps,          // [129][2][64][512] bf16
    signed char* __restrict__ catq,    // [8064][1024] i8 (scale 127)
    int* __restrict__ bar16)           // [2][128][16][FP]
{
  const int blk = blockIdx.x;
  const int dir = blockIdx.y;
  const int tid = threadIdx.x;
  const int l = tid & 63, w = tid >> 6;
  const u16* Whh = Whh_all + (long)dir * G3 * HH;
  const float* bhh = dir ? bhh_b : bhh_f;
  const u16* gx = gx_all + (long)dir * MROWS * G3;

  __shared__ char Wl[96 * 1024];               // 96 rows x 512 bf16, swizzled
  __shared__ __align__(16) u16 hstage[BB][32]; // 4KB bf16 repack tile
  __shared__ __align__(8) signed char hstageq[BB][32]; // 2KB i8 repack tile

  for (int c = tid; c < 6144; c += 256) {
    int lr = c >> 6;
    int k8 = c & 63;
    int gr = (lr >> 5) * HH + blk * 32 + (lr & 31);
    uint4 v = *(const uint4*)(Whh + (long)gr * HH + k8 * 8);
    *(uint4*)(Wl + lr * 1024 + ((k8 * 16) ^ ((lr & 7) << 4))) = v;
  }
  float bh[6];
#pragma unroll
  for (int n = 0; n < 6; n++) {
    int c = n * 16 + (l & 15);
    bh[n] = bhh[(c >> 5) * HH + blk * 32 + (c & 31)];
  }
  float hreg[4][2] = {};
  __syncthreads();

  const int lrow = w * 16 + ((l >> 4) * 4);
  const int srow = tid >> 2, schunk = tid & 3;

  u16 gxn[3][4][2];
  {
    const int lpos0 = dir ? (LL - 1) : 0;
#pragma unroll
    for (int r = 0; r < 4; r++) {
      const u16* gxr = gx + ((long)lpos0 * BB + (lrow + r)) * G3 + blk * 32;
#pragma unroll
      for (int g = 0; g < 3; g++)
#pragma unroll
        for (int p = 0; p < 2; p++)
          gxn[g][r][p] = gxr[g * HH + p * 16 + (l & 15)];
    }
  }

  for (int t = 0; t < LL; ++t) {
    const int lpos = dir ? (LL - 1 - t) : t;
    const u16* hsrc = hsteps + ((size_t)t * 2 + dir) * BB * HH;

    u16 gxv[3][4][2];
#pragma unroll
    for (int g = 0; g < 3; g++)
#pragma unroll
      for (int r = 0; r < 4; r++)
#pragma unroll
        for (int p = 0; p < 2; p++) gxv[g][r][p] = gxn[g][r][p];

    bf16x8 af[16];
    {
      const u16* hrow = hsrc + (w * 16 + (l & 15)) * HH + ((l >> 4) * 8);
#pragma unroll
      for (int kc = 0; kc < 16; kc++) af[kc] = *(const bf16x8*)(hrow + kc * 32);
    }

    f32x4 acc[6];
#pragma unroll
    for (int n = 0; n < 6; n++) acc[n] = {0.f, 0.f, 0.f, 0.f};
#pragma unroll
    for (int kc = 0; kc < 16; kc++) {
      const int kb = kc * 64 + ((l >> 4) * 16);
#pragma unroll
      for (int n = 0; n < 6; n++) {
        int lr = n * 16 + (l & 15);
        bf16x8 bfr = *(const bf16x8*)(Wl + lr * 1024 + (kb ^ ((l & 7) << 4)));
        acc[n] = __builtin_amdgcn_mfma_f32_16x16x32_bf16(af[kc], bfr, acc[n], 0, 0, 0);
      }
    }

#pragma unroll
    for (int r = 0; r < 4; r++) {
#pragma unroll
      for (int p = 0; p < 2; p++) {
        float ghr = acc[0 + p][r] + bh[0 + p];
        float ghz = acc[2 + p][r] + bh[2 + p];
        float ghn = acc[4 + p][r] + bh[4 + p];
        float xr = bf2f(gxv[0][r][p]);
        float xz = bf2f(gxv[1][r][p]);
        float xn = bf2f(gxv[2][r][p]);
        float ar = fminf(fmaxf(xr + ghr, -30.f), 30.f);
        float az = fminf(fmaxf(xz + ghz, -30.f), 30.f);
        float rg = 1.f / (1.f + __expf(-ar));
        float zg = 1.f / (1.f + __expf(-az));
        float an = fminf(fmaxf(xn + rg * ghn, -30.f), 30.f);
        float e2 = __expf(-2.f * an);
        float ng = (1.f - e2) / (1.f + e2);
        float hn = (1.f - zg) * ng + zg * hreg[r][p];
        hreg[r][p] = hn;
        hstage[lrow + r][p * 16 + (l & 15)] = f2bf(hn);
        hstageq[lrow + r][p * 16 + (l & 15)] = q8(hn * 127.f);
      }
    }
    __syncthreads();

    u32x4 hv = *(const u32x4*)&hstage[srow][schunk * 8];
    u64 hq = *(const u64*)&hstageq[srow][schunk * 8];
    if (t < LL - 1) {
      u16* hdst = hsteps + ((size_t)(t + 1) * 2 + dir) * BB * HH;
      cstore16(hdst + srow * HH + blk * 32 + schunk * 8, hv);
      asm volatile("s_waitcnt vmcnt(0)" ::: "memory");
      __syncthreads();
      if (tid == 0)
        flagstore4(&bar16[((dir * LL + t) * 16 + blk) * FP], 1);
      {
        const int lposn = dir ? (LL - 2 - t) : (t + 1);
#pragma unroll
        for (int r = 0; r < 4; r++) {
          const u16* gxr = gx + ((long)lposn * BB + (lrow + r)) * G3 + blk * 32;
#pragma unroll
          for (int g = 0; g < 3; g++)
#pragma unroll
            for (int p = 0; p < 2; p++)
              gxn[g][r][p] = gxr[g * HH + p * 16 + (l & 15)];
        }
      }
      if (dir == 0) {
        if (lpos < LL - 2)
          *(u64*)(catq + ((long)lpos * BB + srow) * D2H + blk * 32 + schunk * 8) = hq;
      } else {
        if (lpos >= 2)
          *(u64*)(catq + ((long)(lpos - 2) * BB + srow) * D2H + HH + blk * 32 + schunk * 8) = hq;
      }
      const int* flg = bar16 + (dir * LL + t) * 16 * FP;
      for (;;) {
        int v = 1;
        if (l < 16) v = flagload4(&flg[l * FP]);
        if (__all(v != 0)) break;
      }
      __builtin_amdgcn_sched_barrier(0);
    } else {
      if (dir == 0) {
        if (lpos < LL - 2)
          *(u64*)(catq + ((long)lpos * BB + srow) * D2H + blk * 32 + schunk * 8) = hq;
      } else {
        if (lpos >= 2)
          *(u64*)(catq + ((long)(lpos - 2) * BB + srow) * D2H + HH + blk * 32 + schunk * 8) = hq;
      }
    }
  }
}

// ---------------- log-softmax, f32 in-place (fallback) ----------------
__global__ __launch_bounds__(256) void k_lsm(float* __restrict__ out) {
  const long row = blockIdx.x;
  float* p = out + row * VV;
  const int tid = threadIdx.x;
  const int l = tid & 63, w = tid >> 6;
  __shared__ float red[8];

  float4 v[10];
  float m = -1e30f;
#pragma unroll
  for (int j = 0; j < 10; j++) {
    int idx = j * 256 + tid;
    if (idx < 2500) {
      v[j] = *(float4*)(p + idx * 4);
      m = fmaxf(m, fmaxf(fmaxf(v[j].x, v[j].y), fmaxf(v[j].z, v[j].w)));
    }
  }
#pragma unroll
  for (int off = 32; off; off >>= 1) m = fmaxf(m, __shfl_xor(m, off));
  if (l == 0) red[w] = m;
  __syncthreads();
  m = fmaxf(fmaxf(red[0], red[1]), fmaxf(red[2], red[3]));

  float s = 0.f;
#pragma unroll
  for (int j = 0; j < 10; j++) {
    int idx = j * 256 + tid;
    if (idx < 2500) {
      s += __expf(v[j].x - m) + __expf(v[j].y - m) + __expf(v[j].z - m) + __expf(v[j].w - m);
    }
  }
#pragma unroll
  for (int off = 32; off; off >>= 1) s += __shfl_xor(s, off);
  if (l == 0) red[4 + w] = s;
  __syncthreads();
  s = red[4] + red[5] + red[6] + red[7];
  float lse = m + logf(s);

#pragma unroll
  for (int j = 0; j < 10; j++) {
    int idx = j * 256 + tid;
    if (idx < 2500) {
      float4 o;
      o.x = v[j].x - lse; o.y = v[j].y - lse; o.z = v[j].z - lse; o.w = v[j].w - lse;
      *(float4*)(p + idx * 4) = o;
    }
  }
}

// ---------------- log-softmax, bf16 logits -> f32 out ----------------
__global__ __launch_bounds__(256) void k_lsm_b(const u16* __restrict__ lg,
                                               float* __restrict__ out) {
  const long row = blockIdx.x;
  const u16* p = lg + row * NPAD;
  float* q = out + row * VV;
  const int tid = threadIdx.x;
  const int l = tid & 63, w = tid >> 6;
  __shared__ float red[8];

  float v[5][8];
  float m = -1e30f;
#pragma unroll
  for (int j = 0; j < 5; j++) {
    int idx8 = j * 256 + tid;          // 8-elem chunk index, 1250 total
    if (idx8 < 1250) {
      u32x4 u = *(const u32x4*)(p + idx8 * 8);
#pragma unroll
      for (int e = 0; e < 4; e++) {
        v[j][2 * e]     = bf2f((u16)(u[e] & 0xffffu));
        v[j][2 * e + 1] = bf2f((u16)(u[e] >> 16));
      }
#pragma unroll
      for (int e = 0; e < 8; e++) m = fmaxf(m, v[j][e]);
    }
  }
#pragma unroll
  for (int off = 32; off; off >>= 1) m = fmaxf(m, __shfl_xor(m, off));
  if (l == 0) red[w] = m;
  __syncthreads();
  m = fmaxf(fmaxf(red[0], red[1]), fmaxf(red[2], red[3]));

  float s = 0.f;
#pragma unroll
  for (int j = 0; j < 5; j++) {
    int idx8 = j * 256 + tid;
    if (idx8 < 1250) {
#pragma unroll
      for (int e = 0; e < 8; e++) s += __expf(v[j][e] - m);
    }
  }
#pragma unroll
  for (int off = 32; off; off >>= 1) s += __shfl_xor(s, off);
  if (l == 0) red[4 + w] = s;
  __syncthreads();
  s = red[4] + red[5] + red[6] + red[7];
  float lse = m + logf(s);

#pragma unroll
  for (int j = 0; j < 5; j++) {
    int idx8 = j * 256 + tid;
    if (idx8 < 1250) {
      float4 a, b;
      a.x = v[j][0] - lse; a.y = v[j][1] - lse; a.z = v[j][2] - lse; a.w = v[j][3] - lse;
      b.x = v[j][4] - lse; b.y = v[j][5] - lse; b.z = v[j][6] - lse; b.w = v[j][7] - lse;
      *(float4*)(q + idx8 * 8) = a;
      *(float4*)(q + idx8 * 8 + 4) = b;
    }
  }
}

// ---------------- launch ----------------
extern "C" void kernel_launch(void* const* d_in, const int* in_sizes, int n_in,
                              void* d_out, int out_size, void* d_ws, size_t ws_size,
                              hipStream_t stream) {
  const int*   seq  = (const int*)d_in[0];
  const float* emb  = (const float*)d_in[2];
  const float* Wihf = (const float*)d_in[3];
  const float* Whhf = (const float*)d_in[4];
  const float* bihf = (const float*)d_in[5];
  const float* bhhf = (const float*)d_in[6];
  const float* Wihb = (const float*)d_in[7];
  const float* Whhb = (const float*)d_in[8];
  const float* bihb = (const float*)d_in[9];
  const float* bhhb = (const float*)d_in[10];
  const float* decW = (const float*)d_in[11];
  const float* decb = (const float*)d_in[12];

  char* ws = (char*)d_ws;
  size_t off = 0;
  u16* Whh_bf = (u16*)(ws + off); off += (size_t)2 * G3 * HH * 2;        // 3.1M
  u16* Wih_bf = (u16*)(ws + off); off += (size_t)2 * G3 * EE * 2;        // 3.1M
  signed char* decWq = (signed char*)(ws + off); off += (size_t)NPAD * 1024; // 10.4M
  float* wscale = (float*)(ws + off); off += (size_t)NPAD * 4;           // 40K
  u16* xb = (u16*)(ws + off); off += (size_t)MROWS * EE * 2;             // 8.4M
  u16* gxb = (u16*)(ws + off); off += (size_t)2 * MROWS * G3 * 2;        // 50.3M
  signed char* catq = (signed char*)(ws + off); off += (size_t)DM * D2H; // 8.25M
  u16* hsteps = (u16*)(ws + off); off += (size_t)(LL + 1) * 2 * BB * HH * 2; // 16.9M
  int* bar16 = (int*)(ws + off); off += (size_t)2 * LL * 16 * FP * 4;    // 2M
  u16* logitsb = (u16*)(ws + off);
  const size_t logits_bytes = (size_t)DM * NPAD * 2;                     // 163M
  const bool use_bf16_logits = (ws_size >= off + logits_bytes);

  (void)hipMemsetAsync(hsteps, 0, (size_t)2 * BB * HH * 2, stream);
  (void)hipMemsetAsync(bar16, 0, (size_t)2 * LL * 16 * FP * 4, stream);

  const int n4w = G3 * HH / 4;
  k_cast4<<<dim3((n4w + 255) / 256, 4), 256, 0, stream>>>(
      (const float4*)Whhf, (const float4*)Whhb, (const float4*)Wihf, (const float4*)Wihb,
      (ushort4*)Whh_bf, (ushort4*)(Whh_bf + G3 * HH),
      (ushort4*)Wih_bf, (ushort4*)(Wih_bf + G3 * EE), n4w);
  k_quant_w<<<VV, 256, 0, stream>>>(decW, decWq, wscale);
  k_embed<<<MROWS, 128, 0, stream>>>(seq, emb, xb);

  k_gemm_gx<<<dim3(64, 12, 2), 256, 0, stream>>>(xb, Wih_bf, Wih_bf + G3 * EE,
                                                 bihf, bihb, gxb);

  k_gru<<<dim3(16, 2), 256, 0, stream>>>(Whh_bf, bhhf, bhhb, gxb, hsteps, catq, bar16);

  if (use_bf16_logits) {
    k_gemm_i8<1><<<dim3(63, 79), 256, 0, stream>>>(catq, decWq, wscale, decb, logitsb);
    k_lsm_b<<<DM, 256, 0, stream>>>(logitsb, (float*)d_out);
  } else {
    k_gemm_i8<0><<<dim3(63, 79), 256, 0, stream>>>(catq, decWq, wscale, decb, d_out);
    k_lsm<<<DM, 256, 0, stream>>>((float*)d_out);
  }
}

// Round 15
// 982.178 us; speedup vs baseline: 1.5883x; 1.1184x over previous
//
#include <hip/hip_runtime.h>
#include <hip/hip_bf16.h>
#include <stdint.h>

#define LL 128
#define BB 64
#define VV 10000
#define EE 512
#define HH 512
#define G3 1536
#define MROWS 8192      // L*B
#define DM 8064         // (L-2)*B
#define D2H 1024
#define NPAD 10112      // 79*128
#define FP 16           // flag padding (ints) -> one 64B line per producer
#define NTILE_M 63
#define NTILE_N 79

typedef __bf16 bf16x8 __attribute__((ext_vector_type(8)));
typedef float f32x4 __attribute__((ext_vector_type(4)));
typedef int i32x4 __attribute__((ext_vector_type(4)));
typedef unsigned int u32x4 __attribute__((ext_vector_type(4)));
typedef unsigned int u32x2 __attribute__((ext_vector_type(2)));
typedef unsigned short u16;
typedef unsigned long long u64;

static __device__ __forceinline__ float bf2f(u16 u) {
  unsigned int x = ((unsigned int)u) << 16;
  return __builtin_bit_cast(float, x);
}
static __device__ __forceinline__ u16 f2bf(float f) {
  unsigned int x = __builtin_bit_cast(unsigned int, f);
  unsigned int r = x + 0x7FFFu + ((x >> 16) & 1u);
  return (u16)(r >> 16);
}
static __device__ __forceinline__ signed char q8(float v) {
  float r = fminf(fmaxf(rintf(v), -127.f), 127.f);
  return (signed char)(int)r;
}

// device-coherent (L1+L2-bypassing, visible at L3) ops
static __device__ __forceinline__ void cstore16(void* p, u32x4 v) {
  asm volatile("global_store_dwordx4 %0, %1, off sc0 sc1" :: "v"(p), "v"(v) : "memory");
}
static __device__ __forceinline__ void cstore8(void* p, u64 v) {
  u32x2 d = __builtin_bit_cast(u32x2, v);
  asm volatile("global_store_dwordx2 %0, %1, off sc0 sc1" :: "v"(p), "v"(d) : "memory");
}
static __device__ __forceinline__ void flagstore4(void* p, int v) {
  asm volatile("global_store_dword %0, %1, off sc0 sc1" :: "v"(p), "v"(v) : "memory");
}
static __device__ __forceinline__ int flagload4(const void* p) {
  int v;
  asm volatile("global_load_dword %0, %1, off sc0 sc1\n\ts_waitcnt vmcnt(0)"
               : "=v"(v) : "v"(p) : "memory");
  return v;
}
// async global->LDS, 16B per lane: LDS dest = wave-uniform base + lane*16
static __device__ __forceinline__ void gload_lds16(const void* g, void* s) {
  __builtin_amdgcn_global_load_lds(
      (const __attribute__((address_space(1))) unsigned int*)g,
      (__attribute__((address_space(3))) unsigned int*)s, 16, 0, 0);
}

// ---------------- cast / quant kernels ----------------
__global__ void k_cast4(const float4* __restrict__ s0, const float4* __restrict__ s1,
                        const float4* __restrict__ s2, const float4* __restrict__ s3,
                        ushort4* __restrict__ d0, ushort4* __restrict__ d1,
                        ushort4* __restrict__ d2, ushort4* __restrict__ d3, int n4) {
  const float4* s; ushort4* d;
  switch (blockIdx.y) {
    case 0: s = s0; d = d0; break;
    case 1: s = s1; d = d1; break;
    case 2: s = s2; d = d2; break;
    default: s = s3; d = d3; break;
  }
  int i = blockIdx.x * blockDim.x + threadIdx.x;
  if (i < n4) {
    float4 v = s[i];
    ushort4 o;
    o.x = f2bf(v.x); o.y = f2bf(v.y); o.z = f2bf(v.z); o.w = f2bf(v.w);
    d[i] = o;
  }
}

__global__ __launch_bounds__(256) void k_quant_w(const float* __restrict__ W,
                                                 signed char* __restrict__ Q,
                                                 float* __restrict__ wscale) {
  const int v = blockIdx.x;
  const int tid = threadIdx.x;
  const int l = tid & 63, w = tid >> 6;
  float4 x = *(const float4*)(W + (long)v * 1024 + tid * 4);
  float m = fmaxf(fmaxf(fabsf(x.x), fabsf(x.y)), fmaxf(fabsf(x.z), fabsf(x.w)));
#pragma unroll
  for (int off = 32; off; off >>= 1) m = fmaxf(m, __shfl_xor(m, off));
  __shared__ float red[4];
  __shared__ float s_inv;
  if (l == 0) red[w] = m;
  __syncthreads();
  if (tid == 0) {
    float mm = fmaxf(fmaxf(red[0], red[1]), fmaxf(red[2], red[3]));
    mm = fmaxf(mm, 1e-12f);
    s_inv = 127.f / mm;
    wscale[v] = mm / (127.f * 127.f);
  }
  __syncthreads();
  float inv = s_inv;
  char4 o;
  o.x = q8(x.x * inv); o.y = q8(x.y * inv); o.z = q8(x.z * inv); o.w = q8(x.w * inv);
  *(char4*)(Q + (long)v * 1024 + tid * 4) = o;
}

__global__ void k_embed(const int* __restrict__ seq, const float* __restrict__ emb,
                        u16* __restrict__ x) {
  int rb = blockIdx.x;
  int v = seq[rb];
  const float4* s = (const float4*)(emb + (long)v * EE);
  ushort4* d = (ushort4*)(x + (long)rb * EE);
  int t = threadIdx.x;
  float4 val = s[t];
  ushort4 o;
  o.x = f2bf(val.x); o.y = f2bf(val.y); o.z = f2bf(val.z); o.w = f2bf(val.w);
  d[t] = o;
}

// ---------------- gx GEMM (both directions, blockIdx.z selects) -------------
__global__ __launch_bounds__(256) void k_gemm_gx(
    const u16* __restrict__ A, const u16* __restrict__ W0, const u16* __restrict__ W1,
    const float* __restrict__ b0, const float* __restrict__ b1, u16* __restrict__ C)
{
  __shared__ char smem[32768];
  const int tid = threadIdx.x;
  const int l = tid & 63;
  const int w = tid >> 6;
  const int wr = w >> 1, wc = w & 1;
  const long tM = (long)blockIdx.x * 128;
  const long tN = (long)blockIdx.y * 128;
  const int z = blockIdx.z;
  const u16* B = z ? W1 : W0;
  const float* bias = z ? b1 : b0;
  u16* Cz = C + (size_t)z * MROWS * G3;

  f32x4 acc[4][4];
#pragma unroll
  for (int m = 0; m < 4; m++)
#pragma unroll
    for (int n = 0; n < 4; n++) acc[m][n] = {0.f, 0.f, 0.f, 0.f};

  for (int kt = 0; kt < 8; ++kt) {
    const int k0 = kt << 6;
#pragma unroll
    for (int i = 0; i < 4; i++) {
      int cchunk = w * 4 + i;
      int c = cchunk * 64 + l;
      int row = c >> 3, k8 = c & 7;
      gload_lds16(A + (tM + row) * EE + k0 + k8 * 8, smem + cchunk * 1024);
      gload_lds16(B + (tN + row) * EE + k0 + k8 * 8, smem + 16384 + cchunk * 1024);
    }
    __syncthreads();
#pragma unroll
    for (int kk = 0; kk < 2; kk++) {
      const int kb = kk * 64 + ((l >> 4) * 16);
      bf16x8 af[4], bfr[4];
#pragma unroll
      for (int m = 0; m < 4; m++) {
        int ra = wr * 64 + m * 16 + (l & 15);
        af[m] = *(const bf16x8*)(smem + ra * 128 + kb);
      }
#pragma unroll
      for (int n = 0; n < 4; n++) {
        int rb2 = wc * 64 + n * 16 + (l & 15);
        bfr[n] = *(const bf16x8*)(smem + 16384 + rb2 * 128 + kb);
      }
#pragma unroll
      for (int m = 0; m < 4; m++)
#pragma unroll
        for (int n = 0; n < 4; n++)
          acc[m][n] = __builtin_amdgcn_mfma_f32_16x16x32_bf16(af[m], bfr[n], acc[m][n], 0, 0, 0);
    }
    __syncthreads();
  }
#pragma unroll
  for (int n = 0; n < 4; n++) {
    long col = tN + wc * 64 + n * 16 + (l & 15);
    float bv = bias[col];
#pragma unroll
    for (int m = 0; m < 4; m++) {
      long row = tM + wr * 64 + m * 16 + ((l >> 4) * 4);
#pragma unroll
      for (int r = 0; r < 4; r++)
        Cz[(row + r) * G3 + col] = f2bf(acc[m][n][r] + bv);
    }
  }
}

// ================= fused GRU + persistent decoder =================
// Grid = 256 blocks (== CU count -> all co-resident by capacity; gru blocks
// depend only on each other; decoder blocks wait on gru flags -> acyclic).
// Blocks 0..31: GRU (dir = bid&1, slice = bid>>1).
// Blocks 32..255: persistent i8 decoder workers on a middle-out ticket queue.

static __device__ void gru_body(
    int blk, int dir, int tid, char* lds,
    const u16* __restrict__ Whh_all,
    const float* __restrict__ bhh_f, const float* __restrict__ bhh_b,
    const u16* __restrict__ gx_all, u16* __restrict__ hsteps,
    signed char* __restrict__ catq, int* __restrict__ bar16)
{
  const int l = tid & 63, w = tid >> 6;
  const u16* Whh = Whh_all + (long)dir * G3 * HH;
  const float* bhh = dir ? bhh_b : bhh_f;
  const u16* gx = gx_all + (long)dir * MROWS * G3;

  char* Wl = lds;                                        // 96KB swizzled
  u16 (*hstage)[32] = (u16(*)[32])(lds + 96 * 1024);     // 4KB
  signed char (*hstageq)[32] = (signed char(*)[32])(lds + 96 * 1024 + 4096); // 2KB

  for (int c = tid; c < 6144; c += 256) {
    int lr = c >> 6;
    int k8 = c & 63;
    int gr = (lr >> 5) * HH + blk * 32 + (lr & 31);
    uint4 v = *(const uint4*)(Whh + (long)gr * HH + k8 * 8);
    *(uint4*)(Wl + lr * 1024 + ((k8 * 16) ^ ((lr & 7) << 4))) = v;
  }
  float bh[6];
#pragma unroll
  for (int n = 0; n < 6; n++) {
    int c = n * 16 + (l & 15);
    bh[n] = bhh[(c >> 5) * HH + blk * 32 + (c & 31)];
  }
  float hreg[4][2] = {};
  __syncthreads();

  const int lrow = w * 16 + ((l >> 4) * 4);
  const int srow = tid >> 2, schunk = tid & 3;

  u16 gxn[3][4][2];
  {
    const int lpos0 = dir ? (LL - 1) : 0;
#pragma unroll
    for (int r = 0; r < 4; r++) {
      const u16* gxr = gx + ((long)lpos0 * BB + (lrow + r)) * G3 + blk * 32;
#pragma unroll
      for (int g = 0; g < 3; g++)
#pragma unroll
        for (int p = 0; p < 2; p++)
          gxn[g][r][p] = gxr[g * HH + p * 16 + (l & 15)];
    }
  }

  for (int t = 0; t < LL; ++t) {
    const int lpos = dir ? (LL - 1 - t) : t;
    const u16* hsrc = hsteps + ((size_t)t * 2 + dir) * BB * HH;

    u16 gxv[3][4][2];
#pragma unroll
    for (int g = 0; g < 3; g++)
#pragma unroll
      for (int r = 0; r < 4; r++)
#pragma unroll
        for (int p = 0; p < 2; p++) gxv[g][r][p] = gxn[g][r][p];

    bf16x8 af[16];
    {
      const u16* hrow = hsrc + (w * 16 + (l & 15)) * HH + ((l >> 4) * 8);
#pragma unroll
      for (int kc = 0; kc < 16; kc++) af[kc] = *(const bf16x8*)(hrow + kc * 32);
    }

    f32x4 acc[6];
#pragma unroll
    for (int n = 0; n < 6; n++) acc[n] = {0.f, 0.f, 0.f, 0.f};
#pragma unroll
    for (int kc = 0; kc < 16; kc++) {
      const int kb = kc * 64 + ((l >> 4) * 16);
#pragma unroll
      for (int n = 0; n < 6; n++) {
        int lr = n * 16 + (l & 15);
        bf16x8 bfr = *(const bf16x8*)(Wl + lr * 1024 + (kb ^ ((l & 7) << 4)));
        acc[n] = __builtin_amdgcn_mfma_f32_16x16x32_bf16(af[kc], bfr, acc[n], 0, 0, 0);
      }
    }

#pragma unroll
    for (int r = 0; r < 4; r++) {
#pragma unroll
      for (int p = 0; p < 2; p++) {
        float ghr = acc[0 + p][r] + bh[0 + p];
        float ghz = acc[2 + p][r] + bh[2 + p];
        float ghn = acc[4 + p][r] + bh[4 + p];
        float xr = bf2f(gxv[0][r][p]);
        float xz = bf2f(gxv[1][r][p]);
        float xn = bf2f(gxv[2][r][p]);
        float ar = fminf(fmaxf(xr + ghr, -30.f), 30.f);
        float az = fminf(fmaxf(xz + ghz, -30.f), 30.f);
        float rg = 1.f / (1.f + __expf(-ar));
        float zg = 1.f / (1.f + __expf(-az));
        float an = fminf(fmaxf(xn + rg * ghn, -30.f), 30.f);
        float e2 = __expf(-2.f * an);
        float ng = (1.f - e2) / (1.f + e2);
        float hn = (1.f - zg) * ng + zg * hreg[r][p];
        hreg[r][p] = hn;
        hstage[lrow + r][p * 16 + (l & 15)] = f2bf(hn);
        hstageq[lrow + r][p * 16 + (l & 15)] = q8(hn * 127.f);
      }
    }
    __syncthreads();

    u32x4 hv = *(const u32x4*)&hstage[srow][schunk * 8];
    u64 hq = *(const u64*)&hstageq[srow][schunk * 8];
    // coherent stores: next h + catq row — BOTH ack'd before the flag, so a
    // posted flag certifies catq visibility at L3 for the decoder workers.
    if (t < LL - 1)
      cstore16(hsteps + ((size_t)(t + 1) * 2 + dir) * BB * HH + srow * HH + blk * 32 + schunk * 8, hv);
    if (dir == 0) {
      if (lpos < LL - 2)
        cstore8(catq + ((long)lpos * BB + srow) * D2H + blk * 32 + schunk * 8, hq);
    } else {
      if (lpos >= 2)
        cstore8(catq + ((long)(lpos - 2) * BB + srow) * D2H + HH + blk * 32 + schunk * 8, hq);
    }
    if (t < LL - 1) {
      asm volatile("s_waitcnt vmcnt(0)" ::: "memory");
      __syncthreads();
      if (tid == 0)
        flagstore4(&bar16[((dir * LL + t) * 16 + blk) * FP], 1);
      {
        const int lposn = dir ? (LL - 2 - t) : (t + 1);
#pragma unroll
        for (int r = 0; r < 4; r++) {
          const u16* gxr = gx + ((long)lposn * BB + (lrow + r)) * G3 + blk * 32;
#pragma unroll
          for (int g = 0; g < 3; g++)
#pragma unroll
            for (int p = 0; p < 2; p++)
              gxn[g][r][p] = gxr[g * HH + p * 16 + (l & 15)];
        }
      }
      const int* flg = bar16 + (dir * LL + t) * 16 * FP;
      for (;;) {
        int v = 1;
        if (l < 16) v = flagload4(&flg[l * FP]);
        if (__all(v != 0)) break;
      }
      __builtin_amdgcn_sched_barrier(0);
    }
  }
}

static __device__ void dec_body(
    int tid, char* smem, int* tk_sh,
    const signed char* __restrict__ A, const signed char* __restrict__ B,
    const float* __restrict__ wscale, const float* __restrict__ bias,
    void* __restrict__ Cv, int outbf,
    int* __restrict__ ticket, const int* __restrict__ bar16)
{
  const int l = tid & 63;
  const int w = tid >> 6;
  const int wr = w >> 1, wc = w & 1;

  for (;;) {
    if (tid == 0)
      *tk_sh = __hip_atomic_fetch_add(ticket, 1, __ATOMIC_RELAXED, __HIP_MEMORY_SCOPE_AGENT);
    __syncthreads();
    const int n = *tk_sh;
    __syncthreads();
    if (n >= NTILE_M * NTILE_N) return;
    const int k = n / NTILE_N, j = n % NTILE_N;
    const int mi = (k & 1) ? (31 + ((k + 1) >> 1)) : (31 - (k >> 1));
    const long tM = (long)mi * 128;
    const long tN = (long)j * 128;

    // readiness: fwd flag t=2mi+1 covers rows {2mi,2mi+1}; bwd flag t=125-2mi
    // covers both (earlier same-producer flags are cumulatively visible).
    {
      const int tf = 2 * mi + 1;
      const int tb = 125 - 2 * mi;
      const int* fp = (l < 16)
          ? bar16 + ((0 * LL + tf) * 16 + l) * FP
          : bar16 + ((1 * LL + tb) * 16 + (l & 15)) * FP;
      for (;;) {
        int v = 1;
        if (l < 32) v = flagload4(fp);
        if (__all(v != 0)) break;
      }
    }

    i32x4 acc[4][4];
#pragma unroll
    for (int m = 0; m < 4; m++)
#pragma unroll
      for (int nn = 0; nn < 4; nn++) acc[m][nn] = {0, 0, 0, 0};

    for (int kt = 0; kt < 8; ++kt) {
      const int k0 = kt << 7;
#pragma unroll
      for (int i = 0; i < 4; i++) {
        int jj = w * 4 + i;
        int row = jj * 8 + (l >> 3);
        int k16 = l & 7;
        gload_lds16(A + (tM + row) * 1024 + k0 + k16 * 16, smem + jj * 1024);
        gload_lds16(B + (tN + row) * 1024 + k0 + k16 * 16, smem + 16384 + jj * 1024);
      }
      __syncthreads();
#pragma unroll
      for (int ks = 0; ks < 2; ks++) {
        const int kb = ks * 64 + ((l >> 4) * 16);
        i32x4 af[4], bfr[4];
#pragma unroll
        for (int m = 0; m < 4; m++) {
          int ra = wr * 64 + m * 16 + (l & 15);
          af[m] = *(const i32x4*)(smem + ra * 128 + kb);
        }
#pragma unroll
        for (int nn = 0; nn < 4; nn++) {
          int rb2 = wc * 64 + nn * 16 + (l & 15);
          bfr[nn] = *(const i32x4*)(smem + 16384 + rb2 * 128 + kb);
        }
#pragma unroll
        for (int m = 0; m < 4; m++)
#pragma unroll
          for (int nn = 0; nn < 4; nn++)
            acc[m][nn] = __builtin_amdgcn_mfma_i32_16x16x64_i8(af[m], bfr[nn], acc[m][nn], 0, 0, 0);
      }
      __syncthreads();
    }
#pragma unroll
    for (int nn = 0; nn < 4; nn++) {
      long col = tN + wc * 64 + nn * 16 + (l & 15);
      if (col < VV) {
        float sc = wscale[col];
        float bv = bias[col];
#pragma unroll
        for (int m = 0; m < 4; m++) {
          long row = tM + wr * 64 + m * 16 + ((l >> 4) * 4);
#pragma unroll
          for (int r = 0; r < 4; r++) {
            float vv = (float)acc[m][nn][r] * sc + bv;
            if (outbf) ((u16*)Cv)[(row + r) * NPAD + col] = f2bf(vv);
            else       ((float*)Cv)[(row + r) * VV + col] = vv;
          }
        }
      }
    }
  }
}

__global__ __launch_bounds__(256) void k_fused(
    const u16* __restrict__ Whh_all,
    const float* __restrict__ bhh_f, const float* __restrict__ bhh_b,
    const u16* __restrict__ gx_all, u16* __restrict__ hsteps,
    signed char* __restrict__ catq, int* __restrict__ bar16,
    const signed char* __restrict__ decWq, const float* __restrict__ wscale,
    const float* __restrict__ decb, void* __restrict__ Cv, int outbf,
    int* __restrict__ ticket)
{
  __shared__ __align__(16) char lds[104448];
  __shared__ int tk_sh;
  const int bid = blockIdx.x;
  const int tid = threadIdx.x;
  if (bid < 32) {
    gru_body(bid >> 1, bid & 1, tid, lds, Whh_all, bhh_f, bhh_b, gx_all,
             hsteps, catq, bar16);
  } else {
    dec_body(tid, lds, &tk_sh, catq, decWq, wscale, decb, Cv, outbf, ticket, bar16);
  }
}

// ---------------- log-softmax, f32 in-place (fallback) ----------------
__global__ __launch_bounds__(256) void k_lsm(float* __restrict__ out) {
  const long row = blockIdx.x;
  float* p = out + row * VV;
  const int tid = threadIdx.x;
  const int l = tid & 63, w = tid >> 6;
  __shared__ float red[8];

  float4 v[10];
  float m = -1e30f;
#pragma unroll
  for (int j = 0; j < 10; j++) {
    int idx = j * 256 + tid;
    if (idx < 2500) {
      v[j] = *(float4*)(p + idx * 4);
      m = fmaxf(m, fmaxf(fmaxf(v[j].x, v[j].y), fmaxf(v[j].z, v[j].w)));
    }
  }
#pragma unroll
  for (int off = 32; off; off >>= 1) m = fmaxf(m, __shfl_xor(m, off));
  if (l == 0) red[w] = m;
  __syncthreads();
  m = fmaxf(fmaxf(red[0], red[1]), fmaxf(red[2], red[3]));

  float s = 0.f;
#pragma unroll
  for (int j = 0; j < 10; j++) {
    int idx = j * 256 + tid;
    if (idx < 2500) {
      s += __expf(v[j].x - m) + __expf(v[j].y - m) + __expf(v[j].z - m) + __expf(v[j].w - m);
    }
  }
#pragma unroll
  for (int off = 32; off; off >>= 1) s += __shfl_xor(s, off);
  if (l == 0) red[4 + w] = s;
  __syncthreads();
  s = red[4] + red[5] + red[6] + red[7];
  float lse = m + logf(s);

#pragma unroll
  for (int j = 0; j < 10; j++) {
    int idx = j * 256 + tid;
    if (idx < 2500) {
      float4 o;
      o.x = v[j].x - lse; o.y = v[j].y - lse; o.z = v[j].z - lse; o.w = v[j].w - lse;
      *(float4*)(p + idx * 4) = o;
    }
  }
}

// ---------------- log-softmax, bf16 logits -> f32 out ----------------
__global__ __launch_bounds__(256) void k_lsm_b(const u16* __restrict__ lg,
                                               float* __restrict__ out) {
  const long row = blockIdx.x;
  const u16* p = lg + row * NPAD;
  float* q = out + row * VV;
  const int tid = threadIdx.x;
  const int l = tid & 63, w = tid >> 6;
  __shared__ float red[8];

  float v[5][8];
  float m = -1e30f;
#pragma unroll
  for (int j = 0; j < 5; j++) {
    int idx8 = j * 256 + tid;
    if (idx8 < 1250) {
      u32x4 u = *(const u32x4*)(p + idx8 * 8);
#pragma unroll
      for (int e = 0; e < 4; e++) {
        v[j][2 * e]     = bf2f((u16)(u[e] & 0xffffu));
        v[j][2 * e + 1] = bf2f((u16)(u[e] >> 16));
      }
#pragma unroll
      for (int e = 0; e < 8; e++) m = fmaxf(m, v[j][e]);
    }
  }
#pragma unroll
  for (int off = 32; off; off >>= 1) m = fmaxf(m, __shfl_xor(m, off));
  if (l == 0) red[w] = m;
  __syncthreads();
  m = fmaxf(fmaxf(red[0], red[1]), fmaxf(red[2], red[3]));

  float s = 0.f;
#pragma unroll
  for (int j = 0; j < 5; j++) {
    int idx8 = j * 256 + tid;
    if (idx8 < 1250) {
#pragma unroll
      for (int e = 0; e < 8; e++) s += __expf(v[j][e] - m);
    }
  }
#pragma unroll
  for (int off = 32; off; off >>= 1) s += __shfl_xor(s, off);
  if (l == 0) red[4 + w] = s;
  __syncthreads();
  s = red[4] + red[5] + red[6] + red[7];
  float lse = m + logf(s);

#pragma unroll
  for (int j = 0; j < 5; j++) {
    int idx8 = j * 256 + tid;
    if (idx8 < 1250) {
      float4 a, b;
      a.x = v[j][0] - lse; a.y = v[j][1] - lse; a.z = v[j][2] - lse; a.w = v[j][3] - lse;
      b.x = v[j][4] - lse; b.y = v[j][5] - lse; b.z = v[j][6] - lse; b.w = v[j][7] - lse;
      *(float4*)(q + idx8 * 8) = a;
      *(float4*)(q + idx8 * 8 + 4) = b;
    }
  }
}

// ---------------- launch ----------------
extern "C" void kernel_launch(void* const* d_in, const int* in_sizes, int n_in,
                              void* d_out, int out_size, void* d_ws, size_t ws_size,
                              hipStream_t stream) {
  const int*   seq  = (const int*)d_in[0];
  const float* emb  = (const float*)d_in[2];
  const float* Wihf = (const float*)d_in[3];
  const float* Whhf = (const float*)d_in[4];
  const float* bihf = (const float*)d_in[5];
  const float* bhhf = (const float*)d_in[6];
  const float* Wihb = (const float*)d_in[7];
  const float* Whhb = (const float*)d_in[8];
  const float* bihb = (const float*)d_in[9];
  const float* bhhb = (const float*)d_in[10];
  const float* decW = (const float*)d_in[11];
  const float* decb = (const float*)d_in[12];

  char* ws = (char*)d_ws;
  size_t off = 0;
  u16* Whh_bf = (u16*)(ws + off); off += (size_t)2 * G3 * HH * 2;        // 3.1M
  u16* Wih_bf = (u16*)(ws + off); off += (size_t)2 * G3 * EE * 2;        // 3.1M
  signed char* decWq = (signed char*)(ws + off); off += (size_t)NPAD * 1024; // 10.4M
  float* wscale = (float*)(ws + off); off += (size_t)NPAD * 4;           // 40K
  u16* xb = (u16*)(ws + off); off += (size_t)MROWS * EE * 2;             // 8.4M
  u16* gxb = (u16*)(ws + off); off += (size_t)2 * MROWS * G3 * 2;        // 50.3M
  signed char* catq = (signed char*)(ws + off); off += (size_t)DM * D2H; // 8.25M
  u16* hsteps = (u16*)(ws + off); off += (size_t)(LL + 1) * 2 * BB * HH * 2; // 16.9M
  int* bar16 = (int*)(ws + off); off += (size_t)2 * LL * 16 * FP * 4;    // 2M
  int* ticket = (int*)(ws + off); off += 64;
  u16* logitsb = (u16*)(ws + off);
  const size_t logits_bytes = (size_t)DM * NPAD * 2;                     // 163M
  const bool use_bf16_logits = (ws_size >= off + logits_bytes);

  (void)hipMemsetAsync(hsteps, 0, (size_t)2 * BB * HH * 2, stream);
  (void)hipMemsetAsync(bar16, 0, (size_t)2 * LL * 16 * FP * 4 + 64, stream);

  const int n4w = G3 * HH / 4;
  k_cast4<<<dim3((n4w + 255) / 256, 4), 256, 0, stream>>>(
      (const float4*)Whhf, (const float4*)Whhb, (const float4*)Wihf, (const float4*)Wihb,
      (ushort4*)Whh_bf, (ushort4*)(Whh_bf + G3 * HH),
      (ushort4*)Wih_bf, (ushort4*)(Wih_bf + G3 * EE), n4w);
  k_quant_w<<<VV, 256, 0, stream>>>(decW, decWq, wscale);
  k_embed<<<MROWS, 128, 0, stream>>>(seq, emb, xb);

  k_gemm_gx<<<dim3(64, 12, 2), 256, 0, stream>>>(xb, Wih_bf, Wih_bf + G3 * EE,
                                                 bihf, bihb, gxb);

  void* Cv = use_bf16_logits ? (void*)logitsb : (void*)d_out;
  k_fused<<<dim3(256), 256, 0, stream>>>(Whh_bf, bhhf, bhhb, gxb, hsteps, catq,
                                         bar16, decWq, wscale, decb, Cv,
                                         use_bf16_logits ? 1 : 0, ticket);

  if (use_bf16_logits) k_lsm_b<<<DM, 256, 0, stream>>>(logitsb, (float*)d_out);
  else                 k_lsm<<<DM, 256, 0, stream>>>((float*)d_out);
}